// Round 3
// baseline (1841.933 us; speedup 1.0000x reference)
//
#include <hip/hip_runtime.h>
#include <hip/hip_bf16.h>

#define EPSV 1e-5f
typedef __hip_bfloat16 bf16;
__device__ __forceinline__ float b2f(bf16 v) { return __bfloat162float(v); }
__device__ __forceinline__ bf16 f2b(float v) { return __float2bfloat16(v); }

__global__ __launch_bounds__(256) void fill_k(float* __restrict__ out, float val, int n)
{
  int i = blockIdx.x * 256 + threadIdx.x;
  if (i < n) out[i] = val;
}

// ---------- conv1 stats: one block per channel, serial-simple ----------
__global__ __launch_bounds__(256) void conv1_stats_k(
    const float* __restrict__ x, const float* __restrict__ w1,
    const float* __restrict__ b1, const float* __restrict__ g,
    const float* __restrict__ bt, float* __restrict__ bnp)
{
  int c = blockIdx.x, t = threadIdx.x;
  float w[9];
#pragma unroll
  for (int j = 0; j < 9; ++j) w[j] = w1[c * 9 + j];
  float bias = b1[c];
  float s = 0.f, ss = 0.f;
  for (int img = t; img < 2048; img += 256) {
    const float* xb = x + img * 1024;
    for (int y = 0; y < 30; ++y) {
      const float* r0 = xb + y * 32;
      for (int xx = 0; xx < 30; ++xx) {
        float v = bias;
        v = fmaf(r0[xx], w[0], v);      v = fmaf(r0[xx + 1], w[1], v);  v = fmaf(r0[xx + 2], w[2], v);
        v = fmaf(r0[xx + 32], w[3], v); v = fmaf(r0[xx + 33], w[4], v); v = fmaf(r0[xx + 34], w[5], v);
        v = fmaf(r0[xx + 64], w[6], v); v = fmaf(r0[xx + 65], w[7], v); v = fmaf(r0[xx + 66], w[8], v);
        s += v; ss = fmaf(v, v, ss);
      }
    }
  }
  __shared__ float rs[256], rss[256];
  rs[t] = s; rss[t] = ss;
  __syncthreads();
  if (t == 0) {
    float S = 0.f, SS = 0.f;
    for (int i = 0; i < 256; ++i) { S += rs[i]; SS += rss[i]; }
    const float invn = 1.f / (2048.f * 900.f);
    float mean = S * invn;
    float var = SS * invn - mean * mean;
    float sc = g[c] / sqrtf(var + EPSV);
    bnp[2 * c] = sc;
    bnp[2 * c + 1] = bt[c] - mean * sc;
  }
}

// ---------- conv1 apply: one thread per pooled1 element ----------
__global__ __launch_bounds__(256) void conv1_apply_k(
    const float* __restrict__ x, const float* __restrict__ w1,
    const float* __restrict__ b1, const float* __restrict__ bnp,
    bf16* __restrict__ pooled1)
{
  int gid = blockIdx.x * 256 + threadIdx.x;   // exactly 2048*32*225
  int img = gid / 7200, r = gid - img * 7200;
  int c = r / 225, pp = r - c * 225;
  int py = pp / 15, px = pp - py * 15;
  float w[9];
#pragma unroll
  for (int j = 0; j < 9; ++j) w[j] = w1[c * 9 + j];
  float bias = b1[c], sc = bnp[2 * c], sh = bnp[2 * c + 1];
  const float* xb = x + img * 1024 + (2 * py) * 32 + 2 * px;
  float acc = 0.f;
#pragma unroll
  for (int i = 0; i < 2; ++i)
#pragma unroll
    for (int j = 0; j < 2; ++j) {
      const float* r0 = xb + i * 32 + j;
      float v = bias;
      v = fmaf(r0[0], w[0], v);  v = fmaf(r0[1], w[1], v);  v = fmaf(r0[2], w[2], v);
      v = fmaf(r0[32], w[3], v); v = fmaf(r0[33], w[4], v); v = fmaf(r0[34], w[5], v);
      v = fmaf(r0[64], w[6], v); v = fmaf(r0[65], w[7], v); v = fmaf(r0[66], w[8], v);
      acc += fmaxf(fmaf(v, sc, sh), 0.f);
    }
  pooled1[gid] = f2b(acc * 0.25f);
}

// ---------- conv2 main: thread=(img,pixel), weights in LDS, no bias (BN absorbs) ----------
__global__ __launch_bounds__(256) void conv2_main_k(
    const bf16* __restrict__ in, const float* __restrict__ w2,
    bf16* __restrict__ out)
{
  __shared__ float wls[9216];
  int t = threadIdx.x;
  for (int i = t; i < 9216; i += 256) wls[i] = w2[i];
  __syncthreads();
  int gid = blockIdx.x * 256 + t;            // exactly 2048*169
  int img = gid / 169, pix = gid - img * 169;
  int y = pix / 13, xx = pix - y * 13;
  const bf16* inb = in + img * 7200 + y * 15 + xx;
  float acc[32];
#pragma unroll
  for (int c = 0; c < 32; ++c) acc[c] = 0.f;
  for (int ic = 0; ic < 32; ++ic) {
    const bf16* ip = inb + ic * 225;
    float iv[9];
    iv[0] = b2f(ip[0]);  iv[1] = b2f(ip[1]);  iv[2] = b2f(ip[2]);
    iv[3] = b2f(ip[15]); iv[4] = b2f(ip[16]); iv[5] = b2f(ip[17]);
    iv[6] = b2f(ip[30]); iv[7] = b2f(ip[31]); iv[8] = b2f(ip[32]);
#pragma unroll
    for (int c = 0; c < 32; ++c) {
      const float* wr = wls + c * 288 + ic * 9;
      float v = acc[c];
      v = fmaf(iv[0], wr[0], v); v = fmaf(iv[1], wr[1], v); v = fmaf(iv[2], wr[2], v);
      v = fmaf(iv[3], wr[3], v); v = fmaf(iv[4], wr[4], v); v = fmaf(iv[5], wr[5], v);
      v = fmaf(iv[6], wr[6], v); v = fmaf(iv[7], wr[7], v); v = fmaf(iv[8], wr[8], v);
      acc[c] = v;
    }
  }
  bf16* ob = out + img * 5408 + pix;
#pragma unroll
  for (int c = 0; c < 32; ++c) ob[c * 169] = f2b(acc[c]);
}

// ---------- conv2 stats: one block per channel ----------
__global__ __launch_bounds__(256) void stats2_k(
    const bf16* __restrict__ buf, const float* __restrict__ g,
    const float* __restrict__ bt, float* __restrict__ bnp)
{
  int c = blockIdx.x, t = threadIdx.x;
  float s = 0.f, ss = 0.f;
  for (int f = t; f < 2048 * 169; f += 256) {
    int img = f / 169, p = f - img * 169;
    float v = b2f(buf[img * 5408 + c * 169 + p]);
    s += v; ss = fmaf(v, v, ss);
  }
  __shared__ float rs[256], rss[256];
  rs[t] = s; rss[t] = ss;
  __syncthreads();
  if (t == 0) {
    float S = 0.f, SS = 0.f;
    for (int i = 0; i < 256; ++i) { S += rs[i]; SS += rss[i]; }
    const float invn = 1.f / (2048.f * 169.f);
    float mean = S * invn;
    float var = SS * invn - mean * mean;
    float sc = g[c] / sqrtf(var + EPSV);
    bnp[2 * c] = sc;
    bnp[2 * c + 1] = bt[c] - mean * sc;
  }
}

// ---------- conv2 apply: one thread per pooled2 element ----------
__global__ __launch_bounds__(256) void conv2_apply_k(
    const bf16* __restrict__ in, const float* __restrict__ bnp,
    float* __restrict__ out)
{
  int idx = blockIdx.x * 256 + threadIdx.x;  // exactly 2048*32*36
  int img = idx / 1152, r = idx - img * 1152;
  int c = r / 36, pp = r - c * 36;
  int py = pp / 6, px = pp - py * 6;
  const bf16* bp = in + img * 5408 + c * 169 + py * 26 + px * 2;
  float sc = bnp[2 * c], sh = bnp[2 * c + 1];
  float v = fmaxf(fmaf(b2f(bp[0]), sc, sh), 0.f) + fmaxf(fmaf(b2f(bp[1]), sc, sh), 0.f)
          + fmaxf(fmaf(b2f(bp[13]), sc, sh), 0.f) + fmaxf(fmaf(b2f(bp[14]), sc, sh), 0.f);
  out[idx] = v * 0.25f;
}

// ---------- conv3 main ----------
__global__ __launch_bounds__(256) void conv3_main_k(
    const float* __restrict__ in, const float* __restrict__ w3,
    float* __restrict__ out)
{
  __shared__ float wls[9216];
  int t = threadIdx.x;
  for (int i = t; i < 9216; i += 256) wls[i] = w3[i];
  __syncthreads();
  int gid = blockIdx.x * 256 + t;            // exactly 2048*16
  int img = gid >> 4, pix = gid & 15;
  int y = pix >> 2, xx = pix & 3;
  const float* inb = in + img * 1152 + y * 6 + xx;
  float acc[32];
#pragma unroll
  for (int c = 0; c < 32; ++c) acc[c] = 0.f;
  for (int ic = 0; ic < 32; ++ic) {
    const float* ip = inb + ic * 36;
    float iv[9];
    iv[0] = ip[0];  iv[1] = ip[1];  iv[2] = ip[2];
    iv[3] = ip[6];  iv[4] = ip[7];  iv[5] = ip[8];
    iv[6] = ip[12]; iv[7] = ip[13]; iv[8] = ip[14];
#pragma unroll
    for (int c = 0; c < 32; ++c) {
      const float* wr = wls + c * 288 + ic * 9;
      float v = acc[c];
      v = fmaf(iv[0], wr[0], v); v = fmaf(iv[1], wr[1], v); v = fmaf(iv[2], wr[2], v);
      v = fmaf(iv[3], wr[3], v); v = fmaf(iv[4], wr[4], v); v = fmaf(iv[5], wr[5], v);
      v = fmaf(iv[6], wr[6], v); v = fmaf(iv[7], wr[7], v); v = fmaf(iv[8], wr[8], v);
      acc[c] = v;
    }
  }
  float* ob = out + img * 512 + pix;
#pragma unroll
  for (int c = 0; c < 32; ++c) ob[c * 16] = acc[c];
}

// ---------- conv3 stats: one block per channel ----------
__global__ __launch_bounds__(256) void stats3_k(
    const float* __restrict__ buf, const float* __restrict__ g,
    const float* __restrict__ bt, float* __restrict__ bnp)
{
  int c = blockIdx.x, t = threadIdx.x;
  float s = 0.f, ss = 0.f;
  for (int f = t; f < 2048 * 16; f += 256) {
    int img = f >> 4, p = f & 15;
    float v = buf[img * 512 + c * 16 + p];
    s += v; ss = fmaf(v, v, ss);
  }
  __shared__ float rs[256], rss[256];
  rs[t] = s; rss[t] = ss;
  __syncthreads();
  if (t == 0) {
    float S = 0.f, SS = 0.f;
    for (int i = 0; i < 256; ++i) { S += rs[i]; SS += rss[i]; }
    const float invn = 1.f / (2048.f * 16.f);
    float mean = S * invn;
    float var = SS * invn - mean * mean;
    float sc = g[c] / sqrtf(var + EPSV);
    bnp[2 * c] = sc;
    bnp[2 * c + 1] = bt[c] - mean * sc;
  }
}

// ---------- conv3 apply + pool + broadcast to 4 beams ----------
__global__ __launch_bounds__(256) void conv3_apply_k(
    const float* __restrict__ in, const float* __restrict__ bnp,
    float* __restrict__ hs)
{
  int idx = blockIdx.x * 256 + threadIdx.x;  // exactly 2048*128
  int img = idx >> 7, r = idx & 127;
  int c = r >> 2, q = r & 3;
  int py = q >> 1, px = q & 1;
  const float* bp = in + img * 512 + c * 16 + py * 8 + px * 2;
  float sc = bnp[2 * c], sh = bnp[2 * c + 1];
  float v = (fmaxf(fmaf(bp[0], sc, sh), 0.f) + fmaxf(fmaf(bp[1], sc, sh), 0.f)
           + fmaxf(fmaf(bp[4], sc, sh), 0.f) + fmaxf(fmaf(bp[5], sc, sh), 0.f)) * 0.25f;
  float* hb = hs + img * 512 + r;
  hb[0] = v; hb[128] = v; hb[256] = v; hb[384] = v;
}

// ---------- naive MoE step: thread = (row, out elem), ping-pong ----------
__global__ __launch_bounds__(256) void moe_naive_k(
    const float* __restrict__ hin, float* __restrict__ hout,
    const float* __restrict__ traj, const float* __restrict__ We,
    const float* __restrict__ be, int step)
{
  int gid = blockIdx.x * 256 + threadIdx.x;  // exactly 8192*128
  int row = gid >> 7, h = gid & 127;
  const float* tp = traj + (step * 8192 + row) * 4;
  float t0 = tp[0], t1 = tp[1], t2 = tp[2], t3 = tp[3];
  int e = 0; float bv = t0;
  if (t1 > bv) { bv = t1; e = 1; }
  if (t2 > bv) { bv = t2; e = 2; }
  if (t3 > bv) { bv = t3; e = 3; }
  float v;
  if (e == 3) {
    v = hin[row * 128 + h];
  } else {
    const float* hr = hin + row * 128;
    const float* wp = We + e * 16384 + h;
    float a = be[e * 128 + h];
    for (int d = 0; d < 128; ++d) a = fmaf(hr[d], wp[d * 128], a);
    v = a;
  }
  hout[gid] = fmaxf(v, 0.f);
}

// ---------- naive head ----------
__global__ __launch_bounds__(256) void final_naive_k(
    const float* __restrict__ hs, const float* __restrict__ Wo,
    const float* __restrict__ bo, const float* __restrict__ sv,
    float* __restrict__ out)
{
  int gid = blockIdx.x * 256 + threadIdx.x;  // exactly 8192*10
  int row = gid / 10, o = gid - row * 10;
  float ps = 1.f;
#pragma unroll
  for (int i = 0; i < 12; ++i) ps *= sv[i];
  const float* hr = hs + row * 128;
  const float* wr = Wo + o * 128;
  float a = bo[o];
  for (int d = 0; d < 128; ++d) a = fmaf(hr[d], wr[d], a);
  out[gid] = a * ps;
}

extern "C" void kernel_launch(void* const* d_in, const int* in_sizes, int n_in,
                              void* d_out, int out_size, void* d_ws, size_t ws_size,
                              hipStream_t stream)
{
  float* out = (float*)d_out;

  // ---- diagnostic sentinels: report harness-contract mismatches via absmax ----
  static const int EXP[19] = {2097152, 98304, 12, 288, 32, 9216, 32, 9216, 32,
                              32, 32, 32, 32, 32, 32, 49152, 384, 1280, 10};
  int bad = -1;
  if (n_in != 19) bad = 100;
  else
    for (int i = 0; i < 19; ++i)
      if (in_sizes[i] != EXP[i]) { bad = i; break; }
  if (bad >= 0) {
    fill_k<<<(out_size + 255) / 256, 256, 0, stream>>>(out, 1000.f + 10.f * bad, out_size);
    return;
  }
  const size_t NEED = 73663232;
  if (ws_size < NEED) {
    fill_k<<<(out_size + 255) / 256, 256, 0, stream>>>(
        out, 3000.f + (float)(ws_size >> 20), out_size);
    return;
  }

  const float* x    = (const float*)d_in[0];
  const float* traj = (const float*)d_in[1];
  const float* sv   = (const float*)d_in[2];
  const float* c1w  = (const float*)d_in[3];
  const float* c1b  = (const float*)d_in[4];
  const float* c2w  = (const float*)d_in[5];
  const float* c3w  = (const float*)d_in[7];
  const float* g1   = (const float*)d_in[9];
  const float* bt1  = (const float*)d_in[10];
  const float* g2   = (const float*)d_in[11];
  const float* bt2  = (const float*)d_in[12];
  const float* g3   = (const float*)d_in[13];
  const float* bt3  = (const float*)d_in[14];
  const float* We   = (const float*)d_in[15];
  const float* be   = (const float*)d_in[16];
  const float* Wo   = (const float*)d_in[17];
  const float* bo   = (const float*)d_in[18];

  char* w = (char*)d_ws;
  bf16*  pooled1  = (bf16*)(w + 0);          // 29,491,200 B
  bf16*  conv2out = (bf16*)(w + 29491200);   // 22,151,168 B
  float* pooled2  = (float*)(w + 51642368);  //  9,437,184 B
  float* conv3out = (float*)(w + 61079552);  //  4,194,304 B
  float* hsA      = (float*)(w + 65273856);  //  4,194,304 B
  float* hsB      = (float*)(w + 69468160);  //  4,194,304 B
  float* bnp1     = (float*)(w + 73662464);
  float* bnp2     = (float*)(w + 73662720);
  float* bnp3     = (float*)(w + 73662976);  // end 73,663,232 B

  conv1_stats_k<<<32, 256, 0, stream>>>(x, c1w, c1b, g1, bt1, bnp1);
  conv1_apply_k<<<57600, 256, 0, stream>>>(x, c1w, c1b, bnp1, pooled1);
  conv2_main_k<<<1352, 256, 0, stream>>>(pooled1, c2w, conv2out);
  stats2_k<<<32, 256, 0, stream>>>(conv2out, g2, bt2, bnp2);
  conv2_apply_k<<<9216, 256, 0, stream>>>(conv2out, bnp2, pooled2);
  conv3_main_k<<<128, 256, 0, stream>>>(pooled2, c3w, conv3out);
  stats3_k<<<32, 256, 0, stream>>>(conv3out, g3, bt3, bnp3);
  conv3_apply_k<<<1024, 256, 0, stream>>>(conv3out, bnp3, hsA);
  moe_naive_k<<<4096, 256, 0, stream>>>(hsA, hsB, traj, We, be, 0);
  moe_naive_k<<<4096, 256, 0, stream>>>(hsB, hsA, traj, We, be, 1);
  moe_naive_k<<<4096, 256, 0, stream>>>(hsA, hsB, traj, We, be, 2);
  final_naive_k<<<320, 256, 0, stream>>>(hsB, Wo, bo, sv, out);
}

// Round 4
// 640.249 us; speedup vs baseline: 2.8769x; 2.8769x over previous
//
#include <hip/hip_runtime.h>
#include <hip/hip_bf16.h>

#define EPSV 1e-5f
typedef __hip_bfloat16 bf16;
__device__ __forceinline__ float b2f(bf16 v) { return __bfloat162float(v); }
__device__ __forceinline__ bf16 f2b(float v) { return __float2bfloat16(v); }

__global__ __launch_bounds__(256) void fill_k(float* __restrict__ out, float val, int n)
{
  int i = blockIdx.x * 256 + threadIdx.x;
  if (i < n) out[i] = val;
}

// ---------- conv1 stats pass 1: one block per image -> per-channel partials ----------
__global__ __launch_bounds__(256) void conv1_stats_p1_k(
    const float* __restrict__ x, const float* __restrict__ w1,
    const float* __restrict__ b1, float* __restrict__ partial1)
{
  int img = blockIdx.x, t = threadIdx.x;
  __shared__ __align__(16) float xs[1024];
  ((float4*)xs)[t] = ((const float4*)(x + img * 1024))[t];
  __syncthreads();
  int c = t & 31;
  float w[9];
#pragma unroll
  for (int j = 0; j < 9; ++j) w[j] = w1[c * 9 + j];
  float bias = b1[c];
  float s = 0.f, ss = 0.f;
  for (int p = (t >> 5); p < 900; p += 8) {
    int y = p / 30, xx = p - y * 30;
    const float* r0 = xs + y * 32 + xx;
    float v = bias;
    v = fmaf(r0[0], w[0], v);  v = fmaf(r0[1], w[1], v);  v = fmaf(r0[2], w[2], v);
    v = fmaf(r0[32], w[3], v); v = fmaf(r0[33], w[4], v); v = fmaf(r0[34], w[5], v);
    v = fmaf(r0[64], w[6], v); v = fmaf(r0[65], w[7], v); v = fmaf(r0[66], w[8], v);
    s += v; ss = fmaf(v, v, ss);
  }
  s += __shfl_xor(s, 32, 64);
  ss += __shfl_xor(ss, 32, 64);
  __shared__ float red[4][32][2];
  int wv = t >> 6, lane = t & 63;
  if (lane < 32) { red[wv][lane][0] = s; red[wv][lane][1] = ss; }
  __syncthreads();
  if (t < 64) {
    int cc = t >> 1, j = t & 1;
    partial1[img * 64 + t] = red[0][cc][j] + red[1][cc][j] + red[2][cc][j] + red[3][cc][j];
  }
}

// ---------- conv1 stats pass 2: 32 blocks, reduce 2048 image-partials ----------
__global__ __launch_bounds__(256) void bn_reduce_partial_k(
    const float* __restrict__ partial, const float* __restrict__ g,
    const float* __restrict__ bt, float* __restrict__ bnp,
    int nimg, float invn)
{
  int c = blockIdx.x, t = threadIdx.x;
  float s = 0.f, ss = 0.f;
  for (int i = t; i < nimg; i += 256) {
    s += partial[i * 64 + c * 2];
    ss += partial[i * 64 + c * 2 + 1];
  }
#pragma unroll
  for (int off = 32; off; off >>= 1) { s += __shfl_down(s, off, 64); ss += __shfl_down(ss, off, 64); }
  __shared__ float rs[4], rss[4];
  int wv = t >> 6, lane = t & 63;
  if (lane == 0) { rs[wv] = s; rss[wv] = ss; }
  __syncthreads();
  if (t == 0) {
    s = rs[0] + rs[1] + rs[2] + rs[3];
    ss = rss[0] + rss[1] + rss[2] + rss[3];
    float mean = s * invn;
    float var = ss * invn - mean * mean;
    float sc = g[c] / sqrtf(var + EPSV);
    bnp[2 * c] = sc;
    bnp[2 * c + 1] = bt[c] - mean * sc;
  }
}

// ---------- conv1 apply: block per image, x + weights staged in LDS ----------
__global__ __launch_bounds__(256) void conv1_apply_k(
    const float* __restrict__ x, const float* __restrict__ w1,
    const float* __restrict__ b1, const float* __restrict__ bnp,
    bf16* __restrict__ pooled1)
{
  int img = blockIdx.x, t = threadIdx.x;
  __shared__ __align__(16) float xs[1024];
  __shared__ float wsm[288 + 96];
  ((float4*)xs)[t] = ((const float4*)(x + img * 1024))[t];
  for (int i = t; i < 288; i += 256) wsm[i] = w1[i];     // FIX: full 288 staged
  if (t < 32) { wsm[288 + t] = b1[t]; wsm[320 + t] = bnp[2 * t]; wsm[352 + t] = bnp[2 * t + 1]; }
  __syncthreads();
  bf16* outp = pooled1 + img * 7200;
  for (int idx = t; idx < 7200; idx += 256) {
    int c = idx / 225, pp = idx - c * 225;
    int py = pp / 15, px = pp - py * 15;
    int y0 = 2 * py, x0 = 2 * px;
    const float* wc = wsm + c * 9;
    float bias = wsm[288 + c], sc = wsm[320 + c], sh = wsm[352 + c];
    float r = 0.f;
#pragma unroll
    for (int i = 0; i < 2; ++i)
#pragma unroll
      for (int j = 0; j < 2; ++j) {
        const float* r0 = xs + (y0 + i) * 32 + x0 + j;
        float v = bias;
        v = fmaf(r0[0], wc[0], v);  v = fmaf(r0[1], wc[1], v);  v = fmaf(r0[2], wc[2], v);
        v = fmaf(r0[32], wc[3], v); v = fmaf(r0[33], wc[4], v); v = fmaf(r0[34], wc[5], v);
        v = fmaf(r0[64], wc[6], v); v = fmaf(r0[65], wc[7], v); v = fmaf(r0[66], wc[8], v);
        r += fmaxf(fmaf(v, sc, sh), 0.f);
      }
    outp[idx] = f2b(r * 0.25f);
  }
}

// ---------- conv2 main: thread=(img,pixel), weights in LDS ----------
__global__ __launch_bounds__(256) void conv2_main_k(
    const bf16* __restrict__ in, const float* __restrict__ w2,
    bf16* __restrict__ out)
{
  __shared__ float wls[9216];
  int t = threadIdx.x;
  for (int i = t; i < 9216; i += 256) wls[i] = w2[i];
  __syncthreads();
  int gid = blockIdx.x * 256 + t;            // exactly 2048*169
  int img = gid / 169, pix = gid - img * 169;
  int y = pix / 13, xx = pix - y * 13;
  const bf16* inb = in + img * 7200 + y * 15 + xx;
  float acc[32];
#pragma unroll
  for (int c = 0; c < 32; ++c) acc[c] = 0.f;
  for (int ic = 0; ic < 32; ++ic) {
    const bf16* ip = inb + ic * 225;
    float iv[9];
    iv[0] = b2f(ip[0]);  iv[1] = b2f(ip[1]);  iv[2] = b2f(ip[2]);
    iv[3] = b2f(ip[15]); iv[4] = b2f(ip[16]); iv[5] = b2f(ip[17]);
    iv[6] = b2f(ip[30]); iv[7] = b2f(ip[31]); iv[8] = b2f(ip[32]);
#pragma unroll
    for (int c = 0; c < 32; ++c) {
      const float* wr = wls + c * 288 + ic * 9;
      float v = acc[c];
      v = fmaf(iv[0], wr[0], v); v = fmaf(iv[1], wr[1], v); v = fmaf(iv[2], wr[2], v);
      v = fmaf(iv[3], wr[3], v); v = fmaf(iv[4], wr[4], v); v = fmaf(iv[5], wr[5], v);
      v = fmaf(iv[6], wr[6], v); v = fmaf(iv[7], wr[7], v); v = fmaf(iv[8], wr[8], v);
      acc[c] = v;
    }
  }
  bf16* ob = out + img * 5408 + pix;
#pragma unroll
  for (int c = 0; c < 32; ++c) ob[c * 169] = f2b(acc[c]);
}

// ---------- conv2 stats partials: block = (channel, 256-image slice) ----------
__global__ __launch_bounds__(256) void stats2_p_k(
    const bf16* __restrict__ buf, float* __restrict__ partial)
{
  int c = blockIdx.x & 31, slice = blockIdx.x >> 5;
  int t = threadIdx.x;
  float s = 0.f, ss = 0.f;
  int img0 = slice * 256;
  if (t < 169) {
    for (int im = img0; im < img0 + 256; ++im) {
      float v = b2f(buf[im * 5408 + c * 169 + t]);
      s += v; ss = fmaf(v, v, ss);
    }
  }
#pragma unroll
  for (int off = 32; off; off >>= 1) { s += __shfl_down(s, off, 64); ss += __shfl_down(ss, off, 64); }
  __shared__ float rs[4], rss[4];
  int wv = t >> 6, lane = t & 63;
  if (lane == 0) { rs[wv] = s; rss[wv] = ss; }
  __syncthreads();
  if (t == 0) {
    partial[blockIdx.x * 2] = rs[0] + rs[1] + rs[2] + rs[3];
    partial[blockIdx.x * 2 + 1] = rss[0] + rss[1] + rss[2] + rss[3];
  }
}

// ---------- conv3 stats partials: block = (channel, 256-image slice) ----------
__global__ __launch_bounds__(256) void stats3_p_k(
    const float* __restrict__ buf, float* __restrict__ partial)
{
  int c = blockIdx.x & 31, slice = blockIdx.x >> 5;
  int t = threadIdx.x;
  float s = 0.f, ss = 0.f;
  int img0 = slice * 256;
  for (int f = t; f < 256 * 16; f += 256) {
    int im = img0 + (f >> 4), p = f & 15;
    float v = buf[im * 512 + c * 16 + p];
    s += v; ss = fmaf(v, v, ss);
  }
#pragma unroll
  for (int off = 32; off; off >>= 1) { s += __shfl_down(s, off, 64); ss += __shfl_down(ss, off, 64); }
  __shared__ float rs[4], rss[4];
  int wv = t >> 6, lane = t & 63;
  if (lane == 0) { rs[wv] = s; rss[wv] = ss; }
  __syncthreads();
  if (t == 0) {
    partial[blockIdx.x * 2] = rs[0] + rs[1] + rs[2] + rs[3];
    partial[blockIdx.x * 2 + 1] = rss[0] + rss[1] + rss[2] + rss[3];
  }
}

// ---------- finalize 8-slice partials -> scale/shift ----------
__global__ void bn_finalize_slices_k(
    const float* __restrict__ partial, const float* __restrict__ g,
    const float* __restrict__ bt, float* __restrict__ bnp, float invn)
{
  int c = threadIdx.x;
  if (c < 32) {
    float s = 0.f, ss = 0.f;
#pragma unroll
    for (int sl = 0; sl < 8; ++sl) {
      s += partial[(sl * 32 + c) * 2];
      ss += partial[(sl * 32 + c) * 2 + 1];
    }
    float mean = s * invn;
    float var = ss * invn - mean * mean;
    float sc = g[c] / sqrtf(var + EPSV);
    bnp[2 * c] = sc;
    bnp[2 * c + 1] = bt[c] - mean * sc;
  }
}

// ---------- conv2 apply: one thread per pooled2 element ----------
__global__ __launch_bounds__(256) void conv2_apply_k(
    const bf16* __restrict__ in, const float* __restrict__ bnp,
    float* __restrict__ out)
{
  int idx = blockIdx.x * 256 + threadIdx.x;  // exactly 2048*32*36
  int img = idx / 1152, r = idx - img * 1152;
  int c = r / 36, pp = r - c * 36;
  int py = pp / 6, px = pp - py * 6;
  const bf16* bp = in + img * 5408 + c * 169 + py * 26 + px * 2;
  float sc = bnp[2 * c], sh = bnp[2 * c + 1];
  float v = fmaxf(fmaf(b2f(bp[0]), sc, sh), 0.f) + fmaxf(fmaf(b2f(bp[1]), sc, sh), 0.f)
          + fmaxf(fmaf(b2f(bp[13]), sc, sh), 0.f) + fmaxf(fmaf(b2f(bp[14]), sc, sh), 0.f);
  out[idx] = v * 0.25f;
}

// ---------- conv3 main ----------
__global__ __launch_bounds__(256) void conv3_main_k(
    const float* __restrict__ in, const float* __restrict__ w3,
    float* __restrict__ out)
{
  __shared__ float wls[9216];
  int t = threadIdx.x;
  for (int i = t; i < 9216; i += 256) wls[i] = w3[i];
  __syncthreads();
  int gid = blockIdx.x * 256 + t;            // exactly 2048*16
  int img = gid >> 4, pix = gid & 15;
  int y = pix >> 2, xx = pix & 3;
  const float* inb = in + img * 1152 + y * 6 + xx;
  float acc[32];
#pragma unroll
  for (int c = 0; c < 32; ++c) acc[c] = 0.f;
  for (int ic = 0; ic < 32; ++ic) {
    const float* ip = inb + ic * 36;
    float iv[9];
    iv[0] = ip[0];  iv[1] = ip[1];  iv[2] = ip[2];
    iv[3] = ip[6];  iv[4] = ip[7];  iv[5] = ip[8];
    iv[6] = ip[12]; iv[7] = ip[13]; iv[8] = ip[14];
#pragma unroll
    for (int c = 0; c < 32; ++c) {
      const float* wr = wls + c * 288 + ic * 9;
      float v = acc[c];
      v = fmaf(iv[0], wr[0], v); v = fmaf(iv[1], wr[1], v); v = fmaf(iv[2], wr[2], v);
      v = fmaf(iv[3], wr[3], v); v = fmaf(iv[4], wr[4], v); v = fmaf(iv[5], wr[5], v);
      v = fmaf(iv[6], wr[6], v); v = fmaf(iv[7], wr[7], v); v = fmaf(iv[8], wr[8], v);
      acc[c] = v;
    }
  }
  float* ob = out + img * 512 + pix;
#pragma unroll
  for (int c = 0; c < 32; ++c) ob[c * 16] = acc[c];
}

// ---------- conv3 apply + pool + broadcast to 4 beams ----------
__global__ __launch_bounds__(256) void conv3_apply_k(
    const float* __restrict__ in, const float* __restrict__ bnp,
    float* __restrict__ hs)
{
  int idx = blockIdx.x * 256 + threadIdx.x;  // exactly 2048*128
  int img = idx >> 7, r = idx & 127;
  int c = r >> 2, q = r & 3;
  int py = q >> 1, px = q & 1;
  const float* bp = in + img * 512 + c * 16 + py * 8 + px * 2;
  float sc = bnp[2 * c], sh = bnp[2 * c + 1];
  float v = (fmaxf(fmaf(bp[0], sc, sh), 0.f) + fmaxf(fmaf(bp[1], sc, sh), 0.f)
           + fmaxf(fmaf(bp[4], sc, sh), 0.f) + fmaxf(fmaf(bp[5], sc, sh), 0.f)) * 0.25f;
  float* hb = hs + img * 512 + r;
  hb[0] = v; hb[128] = v; hb[256] = v; hb[384] = v;
}

// ---------- naive MoE step: thread = (row, out elem), ping-pong ----------
__global__ __launch_bounds__(256) void moe_naive_k(
    const float* __restrict__ hin, float* __restrict__ hout,
    const float* __restrict__ traj, const float* __restrict__ We,
    const float* __restrict__ be, int step)
{
  int gid = blockIdx.x * 256 + threadIdx.x;  // exactly 8192*128
  int row = gid >> 7, h = gid & 127;
  const float* tp = traj + (step * 8192 + row) * 4;
  float t0 = tp[0], t1 = tp[1], t2 = tp[2], t3 = tp[3];
  int e = 0; float bv = t0;
  if (t1 > bv) { bv = t1; e = 1; }
  if (t2 > bv) { bv = t2; e = 2; }
  if (t3 > bv) { bv = t3; e = 3; }
  float v;
  if (e == 3) {
    v = hin[row * 128 + h];
  } else {
    const float* hr = hin + row * 128;
    const float* wp = We + e * 16384 + h;
    float a = be[e * 128 + h];
    for (int d = 0; d < 128; ++d) a = fmaf(hr[d], wp[d * 128], a);
    v = a;
  }
  hout[gid] = fmaxf(v, 0.f);
}

// ---------- naive head ----------
__global__ __launch_bounds__(256) void final_naive_k(
    const float* __restrict__ hs, const float* __restrict__ Wo,
    const float* __restrict__ bo, const float* __restrict__ sv,
    float* __restrict__ out)
{
  int gid = blockIdx.x * 256 + threadIdx.x;  // exactly 8192*10
  int row = gid / 10, o = gid - row * 10;
  float ps = 1.f;
#pragma unroll
  for (int i = 0; i < 12; ++i) ps *= sv[i];
  const float* hr = hs + row * 128;
  const float* wr = Wo + o * 128;
  float a = bo[o];
  for (int d = 0; d < 128; ++d) a = fmaf(hr[d], wr[d], a);
  out[gid] = a * ps;
}

extern "C" void kernel_launch(void* const* d_in, const int* in_sizes, int n_in,
                              void* d_out, int out_size, void* d_ws, size_t ws_size,
                              hipStream_t stream)
{
  float* out = (float*)d_out;

  static const int EXP[19] = {2097152, 98304, 12, 288, 32, 9216, 32, 9216, 32,
                              32, 32, 32, 32, 32, 32, 49152, 384, 1280, 10};
  int bad = -1;
  if (n_in != 19) bad = 100;
  else
    for (int i = 0; i < 19; ++i)
      if (in_sizes[i] != EXP[i]) { bad = i; break; }
  if (bad >= 0) {
    fill_k<<<(out_size + 255) / 256, 256, 0, stream>>>(out, 1000.f + 10.f * bad, out_size);
    return;
  }
  const size_t NEED = 73663232;
  if (ws_size < NEED) {
    fill_k<<<(out_size + 255) / 256, 256, 0, stream>>>(
        out, 3000.f + (float)(ws_size >> 20), out_size);
    return;
  }

  const float* x    = (const float*)d_in[0];
  const float* traj = (const float*)d_in[1];
  const float* sv   = (const float*)d_in[2];
  const float* c1w  = (const float*)d_in[3];
  const float* c1b  = (const float*)d_in[4];
  const float* c2w  = (const float*)d_in[5];
  const float* c3w  = (const float*)d_in[7];
  const float* g1   = (const float*)d_in[9];
  const float* bt1  = (const float*)d_in[10];
  const float* g2   = (const float*)d_in[11];
  const float* bt2  = (const float*)d_in[12];
  const float* g3   = (const float*)d_in[13];
  const float* bt3  = (const float*)d_in[14];
  const float* We   = (const float*)d_in[15];
  const float* be   = (const float*)d_in[16];
  const float* Wo   = (const float*)d_in[17];
  const float* bo   = (const float*)d_in[18];

  char* w = (char*)d_ws;
  bf16*  pooled1  = (bf16*)(w + 0);          // 29,491,200 B
  bf16*  conv2out = (bf16*)(w + 29491200);   // 22,151,168 B
  float* pooled2  = (float*)(w + 51642368);  //  9,437,184 B
  float* conv3out = (float*)(w + 61079552);  //  4,194,304 B
  float* hsA      = (float*)(w + 65273856);  //  4,194,304 B
  float* hsB      = (float*)(w + 69468160);  //  4,194,304 B
  float* bnp1     = (float*)(w + 73662464);
  float* bnp2     = (float*)(w + 73662720);
  float* bnp3     = (float*)(w + 73662976);  // end 73,663,232 B
  // short-lived partials aliased into not-yet-written regions (lifetimes disjoint):
  float* partial1 = (float*)conv2out;        // dead before conv2_main writes
  float* partial2 = (float*)pooled2;         // dead before conv2_apply writes
  float* partial3 = (float*)hsA;             // dead before conv3_apply writes

  conv1_stats_p1_k<<<2048, 256, 0, stream>>>(x, c1w, c1b, partial1);
  bn_reduce_partial_k<<<32, 256, 0, stream>>>(partial1, g1, bt1, bnp1, 2048,
                                              1.f / (2048.f * 900.f));
  conv1_apply_k<<<2048, 256, 0, stream>>>(x, c1w, c1b, bnp1, pooled1);
  conv2_main_k<<<1352, 256, 0, stream>>>(pooled1, c2w, conv2out);
  stats2_p_k<<<256, 256, 0, stream>>>(conv2out, partial2);
  bn_finalize_slices_k<<<1, 64, 0, stream>>>(partial2, g2, bt2, bnp2,
                                             1.f / (2048.f * 169.f));
  conv2_apply_k<<<9216, 256, 0, stream>>>(conv2out, bnp2, pooled2);
  conv3_main_k<<<128, 256, 0, stream>>>(pooled2, c3w, conv3out);
  stats3_p_k<<<256, 256, 0, stream>>>(conv3out, partial3);
  bn_finalize_slices_k<<<1, 64, 0, stream>>>(partial3, g3, bt3, bnp3,
                                             1.f / (2048.f * 16.f));
  conv3_apply_k<<<1024, 256, 0, stream>>>(conv3out, bnp3, hsA);
  moe_naive_k<<<4096, 256, 0, stream>>>(hsA, hsB, traj, We, be, 0);
  moe_naive_k<<<4096, 256, 0, stream>>>(hsB, hsA, traj, We, be, 1);
  moe_naive_k<<<4096, 256, 0, stream>>>(hsA, hsB, traj, We, be, 2);
  final_naive_k<<<320, 256, 0, stream>>>(hsB, Wo, bo, sv, out);
}

// Round 5
// 365.147 us; speedup vs baseline: 5.0444x; 1.7534x over previous
//
#include <hip/hip_runtime.h>
#include <hip/hip_bf16.h>

#define EPSV 1e-5f
typedef __hip_bfloat16 bf16;
__device__ __forceinline__ float b2f(bf16 v) { return __bfloat162float(v); }
__device__ __forceinline__ bf16 f2b(float v) { return __float2bfloat16(v); }

__global__ __launch_bounds__(256) void fill_k(float* __restrict__ out, float val, int n)
{
  int i = blockIdx.x * 256 + threadIdx.x;
  if (i < n) out[i] = val;
}

// ---------- transpose conv2/conv3 weights to [(ic*9+k)][oc] ----------
__global__ __launch_bounds__(256) void transpose_w_k(
    const float* __restrict__ w2, const float* __restrict__ w3,
    float* __restrict__ w2t, float* __restrict__ w3t)
{
  int i = blockIdx.x * 256 + threadIdx.x;
  if (i < 9216) {
    int oc = i & 31, rest = i >> 5;     // i = rest*32 + oc, rest = ic*9+k
    w2t[i] = w2[oc * 288 + rest];
  } else if (i < 18432) {
    int j = i - 9216;
    int oc = j & 31, rest = j >> 5;
    w3t[j] = w3[oc * 288 + rest];
  }
}

// ---------- conv1 stats pass 1: one block per image -> per-channel partials ----------
__global__ __launch_bounds__(256) void conv1_stats_p1_k(
    const float* __restrict__ x, const float* __restrict__ w1,
    const float* __restrict__ b1, float* __restrict__ partial1)
{
  int img = blockIdx.x, t = threadIdx.x;
  __shared__ __align__(16) float xs[1024];
  ((float4*)xs)[t] = ((const float4*)(x + img * 1024))[t];
  __syncthreads();
  int c = t & 31;
  float w[9];
#pragma unroll
  for (int j = 0; j < 9; ++j) w[j] = w1[c * 9 + j];
  float bias = b1[c];
  float s = 0.f, ss = 0.f;
  for (int p = (t >> 5); p < 900; p += 8) {
    int y = p / 30, xx = p - y * 30;
    const float* r0 = xs + y * 32 + xx;
    float v = bias;
    v = fmaf(r0[0], w[0], v);  v = fmaf(r0[1], w[1], v);  v = fmaf(r0[2], w[2], v);
    v = fmaf(r0[32], w[3], v); v = fmaf(r0[33], w[4], v); v = fmaf(r0[34], w[5], v);
    v = fmaf(r0[64], w[6], v); v = fmaf(r0[65], w[7], v); v = fmaf(r0[66], w[8], v);
    s += v; ss = fmaf(v, v, ss);
  }
  s += __shfl_xor(s, 32, 64);
  ss += __shfl_xor(ss, 32, 64);
  __shared__ float red[4][32][2];
  int wv = t >> 6, lane = t & 63;
  if (lane < 32) { red[wv][lane][0] = s; red[wv][lane][1] = ss; }
  __syncthreads();
  if (t < 64) {
    int cc = t >> 1, j = t & 1;
    partial1[img * 64 + t] = red[0][cc][j] + red[1][cc][j] + red[2][cc][j] + red[3][cc][j];
  }
}

// ---------- conv1 stats pass 2 ----------
__global__ __launch_bounds__(256) void bn_reduce_partial_k(
    const float* __restrict__ partial, const float* __restrict__ g,
    const float* __restrict__ bt, float* __restrict__ bnp,
    int nimg, float invn)
{
  int c = blockIdx.x, t = threadIdx.x;
  float s = 0.f, ss = 0.f;
  for (int i = t; i < nimg; i += 256) {
    s += partial[i * 64 + c * 2];
    ss += partial[i * 64 + c * 2 + 1];
  }
#pragma unroll
  for (int off = 32; off; off >>= 1) { s += __shfl_down(s, off, 64); ss += __shfl_down(ss, off, 64); }
  __shared__ float rs[4], rss[4];
  int wv = t >> 6, lane = t & 63;
  if (lane == 0) { rs[wv] = s; rss[wv] = ss; }
  __syncthreads();
  if (t == 0) {
    s = rs[0] + rs[1] + rs[2] + rs[3];
    ss = rss[0] + rss[1] + rss[2] + rss[3];
    float mean = s * invn;
    float var = ss * invn - mean * mean;
    float sc = g[c] / sqrtf(var + EPSV);
    bnp[2 * c] = sc;
    bnp[2 * c + 1] = bt[c] - mean * sc;
  }
}

// ---------- conv1 apply: block per image ----------
__global__ __launch_bounds__(256) void conv1_apply_k(
    const float* __restrict__ x, const float* __restrict__ w1,
    const float* __restrict__ b1, const float* __restrict__ bnp,
    bf16* __restrict__ pooled1)
{
  int img = blockIdx.x, t = threadIdx.x;
  __shared__ __align__(16) float xs[1024];
  __shared__ float wsm[288 + 96];
  ((float4*)xs)[t] = ((const float4*)(x + img * 1024))[t];
  for (int i = t; i < 288; i += 256) wsm[i] = w1[i];
  if (t < 32) { wsm[288 + t] = b1[t]; wsm[320 + t] = bnp[2 * t]; wsm[352 + t] = bnp[2 * t + 1]; }
  __syncthreads();
  bf16* outp = pooled1 + img * 7200;
  for (int idx = t; idx < 7200; idx += 256) {
    int c = idx / 225, pp = idx - c * 225;
    int py = pp / 15, px = pp - py * 15;
    int y0 = 2 * py, x0 = 2 * px;
    const float* wc = wsm + c * 9;
    float bias = wsm[288 + c], sc = wsm[320 + c], sh = wsm[352 + c];
    float r = 0.f;
#pragma unroll
    for (int i = 0; i < 2; ++i)
#pragma unroll
      for (int j = 0; j < 2; ++j) {
        const float* r0 = xs + (y0 + i) * 32 + x0 + j;
        float v = bias;
        v = fmaf(r0[0], wc[0], v);  v = fmaf(r0[1], wc[1], v);  v = fmaf(r0[2], wc[2], v);
        v = fmaf(r0[32], wc[3], v); v = fmaf(r0[33], wc[4], v); v = fmaf(r0[34], wc[5], v);
        v = fmaf(r0[64], wc[6], v); v = fmaf(r0[65], wc[7], v); v = fmaf(r0[66], wc[8], v);
        r += fmaxf(fmaf(v, sc, sh), 0.f);
      }
    outp[idx] = f2b(r * 0.25f);
  }
}

// ---------- conv2 main: thread = pixel, weights via wave-uniform scalar loads ----------
__global__ __launch_bounds__(256) void conv2_main_k(
    const bf16* __restrict__ in, const float* __restrict__ w2t,
    bf16* __restrict__ out)
{
  int gid = blockIdx.x * 256 + threadIdx.x;  // exactly 2048*169
  int img = gid / 169, pix = gid - img * 169;
  int y = pix / 13, xx = pix - y * 13;
  const bf16* inb = in + img * 7200 + y * 15 + xx;
  float acc[32];
#pragma unroll
  for (int c = 0; c < 32; ++c) acc[c] = 0.f;
  for (int ic = 0; ic < 32; ++ic) {
    const bf16* ip = inb + ic * 225;
    float iv[9];
    iv[0] = b2f(ip[0]);  iv[1] = b2f(ip[1]);  iv[2] = b2f(ip[2]);
    iv[3] = b2f(ip[15]); iv[4] = b2f(ip[16]); iv[5] = b2f(ip[17]);
    iv[6] = b2f(ip[30]); iv[7] = b2f(ip[31]); iv[8] = b2f(ip[32]);
#pragma unroll
    for (int k = 0; k < 9; ++k) {
      const float* wk = w2t + (ic * 9 + k) * 32;   // uniform address -> s_load
      float v = iv[k];
#pragma unroll
      for (int c = 0; c < 32; ++c) acc[c] = fmaf(v, wk[c], acc[c]);
    }
  }
  bf16* ob = out + img * 5408 + pix;
#pragma unroll
  for (int c = 0; c < 32; ++c) ob[c * 169] = f2b(acc[c]);
}

// ---------- conv2 stats partials ----------
__global__ __launch_bounds__(256) void stats2_p_k(
    const bf16* __restrict__ buf, float* __restrict__ partial)
{
  int c = blockIdx.x & 31, slice = blockIdx.x >> 5;
  int t = threadIdx.x;
  float s = 0.f, ss = 0.f;
  int img0 = slice * 256;
  if (t < 169) {
    for (int im = img0; im < img0 + 256; ++im) {
      float v = b2f(buf[im * 5408 + c * 169 + t]);
      s += v; ss = fmaf(v, v, ss);
    }
  }
#pragma unroll
  for (int off = 32; off; off >>= 1) { s += __shfl_down(s, off, 64); ss += __shfl_down(ss, off, 64); }
  __shared__ float rs[4], rss[4];
  int wv = t >> 6, lane = t & 63;
  if (lane == 0) { rs[wv] = s; rss[wv] = ss; }
  __syncthreads();
  if (t == 0) {
    partial[blockIdx.x * 2] = rs[0] + rs[1] + rs[2] + rs[3];
    partial[blockIdx.x * 2 + 1] = rss[0] + rss[1] + rss[2] + rss[3];
  }
}

// ---------- conv3 stats partials ----------
__global__ __launch_bounds__(256) void stats3_p_k(
    const float* __restrict__ buf, float* __restrict__ partial)
{
  int c = blockIdx.x & 31, slice = blockIdx.x >> 5;
  int t = threadIdx.x;
  float s = 0.f, ss = 0.f;
  int img0 = slice * 256;
  for (int f = t; f < 256 * 16; f += 256) {
    int im = img0 + (f >> 4), p = f & 15;
    float v = buf[im * 512 + c * 16 + p];
    s += v; ss = fmaf(v, v, ss);
  }
#pragma unroll
  for (int off = 32; off; off >>= 1) { s += __shfl_down(s, off, 64); ss += __shfl_down(ss, off, 64); }
  __shared__ float rs[4], rss[4];
  int wv = t >> 6, lane = t & 63;
  if (lane == 0) { rs[wv] = s; rss[wv] = ss; }
  __syncthreads();
  if (t == 0) {
    partial[blockIdx.x * 2] = rs[0] + rs[1] + rs[2] + rs[3];
    partial[blockIdx.x * 2 + 1] = rss[0] + rss[1] + rss[2] + rss[3];
  }
}

// ---------- finalize 8-slice partials ----------
__global__ void bn_finalize_slices_k(
    const float* __restrict__ partial, const float* __restrict__ g,
    const float* __restrict__ bt, float* __restrict__ bnp, float invn)
{
  int c = threadIdx.x;
  if (c < 32) {
    float s = 0.f, ss = 0.f;
#pragma unroll
    for (int sl = 0; sl < 8; ++sl) {
      s += partial[(sl * 32 + c) * 2];
      ss += partial[(sl * 32 + c) * 2 + 1];
    }
    float mean = s * invn;
    float var = ss * invn - mean * mean;
    float sc = g[c] / sqrtf(var + EPSV);
    bnp[2 * c] = sc;
    bnp[2 * c + 1] = bt[c] - mean * sc;
  }
}

// ---------- conv2 apply ----------
__global__ __launch_bounds__(256) void conv2_apply_k(
    const bf16* __restrict__ in, const float* __restrict__ bnp,
    float* __restrict__ out)
{
  int idx = blockIdx.x * 256 + threadIdx.x;  // exactly 2048*32*36
  int img = idx / 1152, r = idx - img * 1152;
  int c = r / 36, pp = r - c * 36;
  int py = pp / 6, px = pp - py * 6;
  const bf16* bp = in + img * 5408 + c * 169 + py * 26 + px * 2;
  float sc = bnp[2 * c], sh = bnp[2 * c + 1];
  float v = fmaxf(fmaf(b2f(bp[0]), sc, sh), 0.f) + fmaxf(fmaf(b2f(bp[1]), sc, sh), 0.f)
          + fmaxf(fmaf(b2f(bp[13]), sc, sh), 0.f) + fmaxf(fmaf(b2f(bp[14]), sc, sh), 0.f);
  out[idx] = v * 0.25f;
}

// ---------- conv3 main: blockIdx.y = oct of 8 output channels ----------
__global__ __launch_bounds__(256) void conv3_main_k(
    const float* __restrict__ in, const float* __restrict__ w3t,
    float* __restrict__ out)
{
  int gid = blockIdx.x * 256 + threadIdx.x;  // exactly 2048*16
  int oct = blockIdx.y;                      // 0..3, wave-uniform
  int img = gid >> 4, pix = gid & 15;
  int y = pix >> 2, xx = pix & 3;
  const float* inb = in + img * 1152 + y * 6 + xx;
  float acc[8];
#pragma unroll
  for (int j = 0; j < 8; ++j) acc[j] = 0.f;
  for (int ic = 0; ic < 32; ++ic) {
    const float* ip = inb + ic * 36;
    float iv[9];
    iv[0] = ip[0];  iv[1] = ip[1];  iv[2] = ip[2];
    iv[3] = ip[6];  iv[4] = ip[7];  iv[5] = ip[8];
    iv[6] = ip[12]; iv[7] = ip[13]; iv[8] = ip[14];
#pragma unroll
    for (int k = 0; k < 9; ++k) {
      const float* wk = w3t + (ic * 9 + k) * 32 + oct * 8;  // uniform -> s_load
      float v = iv[k];
#pragma unroll
      for (int j = 0; j < 8; ++j) acc[j] = fmaf(v, wk[j], acc[j]);
    }
  }
  float* ob = out + img * 512 + (oct * 8) * 16 + pix;
#pragma unroll
  for (int j = 0; j < 8; ++j) ob[j * 16] = acc[j];
}

// ---------- conv3 apply + pool + broadcast to 4 beams ----------
__global__ __launch_bounds__(256) void conv3_apply_k(
    const float* __restrict__ in, const float* __restrict__ bnp,
    float* __restrict__ hs)
{
  int idx = blockIdx.x * 256 + threadIdx.x;  // exactly 2048*128
  int img = idx >> 7, r = idx & 127;
  int c = r >> 2, q = r & 3;
  int py = q >> 1, px = q & 1;
  const float* bp = in + img * 512 + c * 16 + py * 8 + px * 2;
  float sc = bnp[2 * c], sh = bnp[2 * c + 1];
  float v = (fmaxf(fmaf(bp[0], sc, sh), 0.f) + fmaxf(fmaf(bp[1], sc, sh), 0.f)
           + fmaxf(fmaf(bp[4], sc, sh), 0.f) + fmaxf(fmaf(bp[5], sc, sh), 0.f)) * 0.25f;
  float* hb = hs + img * 512 + r;
  hb[0] = v; hb[128] = v; hb[256] = v; hb[384] = v;
}

// ---------- naive MoE step ----------
__global__ __launch_bounds__(256) void moe_naive_k(
    const float* __restrict__ hin, float* __restrict__ hout,
    const float* __restrict__ traj, const float* __restrict__ We,
    const float* __restrict__ be, int step)
{
  int gid = blockIdx.x * 256 + threadIdx.x;  // exactly 8192*128
  int row = gid >> 7, h = gid & 127;
  float4 tv = ((const float4*)traj)[step * 8192 + row];
  int e = 0; float bv = tv.x;
  if (tv.y > bv) { bv = tv.y; e = 1; }
  if (tv.z > bv) { bv = tv.z; e = 2; }
  if (tv.w > bv) { bv = tv.w; e = 3; }
  float v;
  if (e == 3) {
    v = hin[row * 128 + h];
  } else {
    const float* hr = hin + row * 128;     // wave-uniform row
    const float* wp = We + e * 16384 + h;
    float a0 = be[e * 128 + h], a1 = 0.f, a2 = 0.f, a3 = 0.f;
#pragma unroll 8
    for (int d = 0; d < 128; d += 4) {
      a0 = fmaf(hr[d],     wp[d * 128],       a0);
      a1 = fmaf(hr[d + 1], wp[(d + 1) * 128], a1);
      a2 = fmaf(hr[d + 2], wp[(d + 2) * 128], a2);
      a3 = fmaf(hr[d + 3], wp[(d + 3) * 128], a3);
    }
    v = (a0 + a1) + (a2 + a3);
  }
  hout[gid] = fmaxf(v, 0.f);
}

// ---------- naive head ----------
__global__ __launch_bounds__(256) void final_naive_k(
    const float* __restrict__ hs, const float* __restrict__ Wo,
    const float* __restrict__ bo, const float* __restrict__ sv,
    float* __restrict__ out)
{
  int gid = blockIdx.x * 256 + threadIdx.x;  // exactly 8192*10
  int row = gid / 10, o = gid - row * 10;
  float ps = 1.f;
#pragma unroll
  for (int i = 0; i < 12; ++i) ps *= sv[i];
  const float* hr = hs + row * 128;
  const float* wr = Wo + o * 128;
  float a = bo[o];
#pragma unroll 8
  for (int d = 0; d < 128; ++d) a = fmaf(hr[d], wr[d], a);
  out[gid] = a * ps;
}

extern "C" void kernel_launch(void* const* d_in, const int* in_sizes, int n_in,
                              void* d_out, int out_size, void* d_ws, size_t ws_size,
                              hipStream_t stream)
{
  float* out = (float*)d_out;

  static const int EXP[19] = {2097152, 98304, 12, 288, 32, 9216, 32, 9216, 32,
                              32, 32, 32, 32, 32, 32, 49152, 384, 1280, 10};
  int bad = -1;
  if (n_in != 19) bad = 100;
  else
    for (int i = 0; i < 19; ++i)
      if (in_sizes[i] != EXP[i]) { bad = i; break; }
  if (bad >= 0) {
    fill_k<<<(out_size + 255) / 256, 256, 0, stream>>>(out, 1000.f + 10.f * bad, out_size);
    return;
  }
  const size_t NEED = 73663232;
  if (ws_size < NEED) {
    fill_k<<<(out_size + 255) / 256, 256, 0, stream>>>(
        out, 3000.f + (float)(ws_size >> 20), out_size);
    return;
  }

  const float* x    = (const float*)d_in[0];
  const float* traj = (const float*)d_in[1];
  const float* sv   = (const float*)d_in[2];
  const float* c1w  = (const float*)d_in[3];
  const float* c1b  = (const float*)d_in[4];
  const float* c2w  = (const float*)d_in[5];
  const float* c3w  = (const float*)d_in[7];
  const float* g1   = (const float*)d_in[9];
  const float* bt1  = (const float*)d_in[10];
  const float* g2   = (const float*)d_in[11];
  const float* bt2  = (const float*)d_in[12];
  const float* g3   = (const float*)d_in[13];
  const float* bt3  = (const float*)d_in[14];
  const float* We   = (const float*)d_in[15];
  const float* be   = (const float*)d_in[16];
  const float* Wo   = (const float*)d_in[17];
  const float* bo   = (const float*)d_in[18];

  char* w = (char*)d_ws;
  bf16*  pooled1  = (bf16*)(w + 0);          // 29,491,200 B
  bf16*  conv2out = (bf16*)(w + 29491200);   // 22,151,168 B
  float* pooled2  = (float*)(w + 51642368);  //  9,437,184 B
  float* conv3out = (float*)(w + 61079552);  //  4,194,304 B
  float* hsA      = (float*)(w + 65273856);  //  4,194,304 B
  float* hsB      = (float*)(w + 69468160);  //  4,194,304 B
  float* bnp1     = (float*)(w + 73662464);
  float* bnp2     = (float*)(w + 73662720);
  float* bnp3     = (float*)(w + 73662976);  // end 73,663,232 B
  // short-lived buffers aliased into not-yet-written regions (lifetimes disjoint):
  float* partial1 = (float*)conv2out;        // dead before conv2_main writes
  float* partial2 = (float*)pooled2;         // dead before conv2_apply writes
  float* partial3 = (float*)hsA;             // dead before conv3_apply writes
  float* w2t      = (float*)hsB;             // read until conv2_main; hsB written at moe step 0
  float* w3t      = w2t + 9216;              // read until conv3_main

  transpose_w_k<<<72, 256, 0, stream>>>(c2w, c3w, w2t, w3t);
  conv1_stats_p1_k<<<2048, 256, 0, stream>>>(x, c1w, c1b, partial1);
  bn_reduce_partial_k<<<32, 256, 0, stream>>>(partial1, g1, bt1, bnp1, 2048,
                                              1.f / (2048.f * 900.f));
  conv1_apply_k<<<2048, 256, 0, stream>>>(x, c1w, c1b, bnp1, pooled1);
  conv2_main_k<<<1352, 256, 0, stream>>>(pooled1, w2t, conv2out);
  stats2_p_k<<<256, 256, 0, stream>>>(conv2out, partial2);
  bn_finalize_slices_k<<<1, 64, 0, stream>>>(partial2, g2, bt2, bnp2,
                                             1.f / (2048.f * 169.f));
  conv2_apply_k<<<9216, 256, 0, stream>>>(conv2out, bnp2, pooled2);
  conv3_main_k<<<dim3(128, 4), 256, 0, stream>>>(pooled2, w3t, conv3out);
  stats3_p_k<<<256, 256, 0, stream>>>(conv3out, partial3);
  bn_finalize_slices_k<<<1, 64, 0, stream>>>(partial3, g3, bt3, bnp3,
                                             1.f / (2048.f * 16.f));
  conv3_apply_k<<<1024, 256, 0, stream>>>(conv3out, bnp3, hsA);
  moe_naive_k<<<4096, 256, 0, stream>>>(hsA, hsB, traj, We, be, 0);
  moe_naive_k<<<4096, 256, 0, stream>>>(hsB, hsA, traj, We, be, 1);
  moe_naive_k<<<4096, 256, 0, stream>>>(hsA, hsB, traj, We, be, 2);
  final_naive_k<<<320, 256, 0, stream>>>(hsB, Wo, bo, sv, out);
}

// Round 6
// 306.065 us; speedup vs baseline: 6.0181x; 1.1930x over previous
//
#include <hip/hip_runtime.h>
#include <hip/hip_bf16.h>

#define EPSV 1e-5f
typedef __hip_bfloat16 bf16;
typedef __attribute__((ext_vector_type(8))) short v8s;
typedef __attribute__((ext_vector_type(4))) float v4f;
__device__ __forceinline__ float b2f(bf16 v) { return __bfloat162float(v); }
__device__ __forceinline__ bf16 f2b(float v) { return __float2bfloat16(v); }

__global__ __launch_bounds__(256) void fill_k(float* __restrict__ out, float val, int n)
{
  int i = blockIdx.x * 256 + threadIdx.x;
  if (i < n) out[i] = val;
}

// ---------- prep: pack conv2/conv3 weights to [(s)*32+ic][oc] bf16; We -> bf16 ----------
__global__ __launch_bounds__(256) void prep_w_k(
    const float* __restrict__ w2, const float* __restrict__ w3,
    const float* __restrict__ We,
    bf16* __restrict__ w2b, bf16* __restrict__ w3b, bf16* __restrict__ Web)
{
  int i = blockIdx.x * 256 + threadIdx.x;
  if (i < 9216) {
    int oc = i & 31, k = i >> 5, s = k >> 5, ic = k & 31;
    w2b[i] = f2b(w2[oc * 288 + ic * 9 + s]);
  } else if (i < 18432) {
    int j = i - 9216;
    int oc = j & 31, k = j >> 5, s = k >> 5, ic = k & 31;
    w3b[j] = f2b(w3[oc * 288 + ic * 9 + s]);
  } else if (i < 18432 + 49152) {
    int j = i - 18432;
    Web[j] = f2b(We[j]);
  }
}

// ---------- conv1 stats pass 1 ----------
__global__ __launch_bounds__(256) void conv1_stats_p1_k(
    const float* __restrict__ x, const float* __restrict__ w1,
    const float* __restrict__ b1, float* __restrict__ partial1)
{
  int img = blockIdx.x, t = threadIdx.x;
  __shared__ __align__(16) float xs[1024];
  ((float4*)xs)[t] = ((const float4*)(x + img * 1024))[t];
  __syncthreads();
  int c = t & 31;
  float w[9];
#pragma unroll
  for (int j = 0; j < 9; ++j) w[j] = w1[c * 9 + j];
  float bias = b1[c];
  float s = 0.f, ss = 0.f;
  for (int p = (t >> 5); p < 900; p += 8) {
    int y = p / 30, xx = p - y * 30;
    const float* r0 = xs + y * 32 + xx;
    float v = bias;
    v = fmaf(r0[0], w[0], v);  v = fmaf(r0[1], w[1], v);  v = fmaf(r0[2], w[2], v);
    v = fmaf(r0[32], w[3], v); v = fmaf(r0[33], w[4], v); v = fmaf(r0[34], w[5], v);
    v = fmaf(r0[64], w[6], v); v = fmaf(r0[65], w[7], v); v = fmaf(r0[66], w[8], v);
    s += v; ss = fmaf(v, v, ss);
  }
  s += __shfl_xor(s, 32, 64);
  ss += __shfl_xor(ss, 32, 64);
  __shared__ float red[4][32][2];
  int wv = t >> 6, lane = t & 63;
  if (lane < 32) { red[wv][lane][0] = s; red[wv][lane][1] = ss; }
  __syncthreads();
  if (t < 64) {
    int cc = t >> 1, j = t & 1;
    partial1[img * 64 + t] = red[0][cc][j] + red[1][cc][j] + red[2][cc][j] + red[3][cc][j];
  }
}

// ---------- conv1 stats pass 2 ----------
__global__ __launch_bounds__(256) void bn_reduce_partial_k(
    const float* __restrict__ partial, const float* __restrict__ g,
    const float* __restrict__ bt, float* __restrict__ bnp,
    int nimg, float invn)
{
  int c = blockIdx.x, t = threadIdx.x;
  float s = 0.f, ss = 0.f;
  for (int i = t; i < nimg; i += 256) {
    s += partial[i * 64 + c * 2];
    ss += partial[i * 64 + c * 2 + 1];
  }
#pragma unroll
  for (int off = 32; off; off >>= 1) { s += __shfl_down(s, off, 64); ss += __shfl_down(ss, off, 64); }
  __shared__ float rs[4], rss[4];
  int wv = t >> 6, lane = t & 63;
  if (lane == 0) { rs[wv] = s; rss[wv] = ss; }
  __syncthreads();
  if (t == 0) {
    s = rs[0] + rs[1] + rs[2] + rs[3];
    ss = rss[0] + rss[1] + rss[2] + rss[3];
    float mean = s * invn;
    float var = ss * invn - mean * mean;
    float sc = g[c] / sqrtf(var + EPSV);
    bnp[2 * c] = sc;
    bnp[2 * c + 1] = bt[c] - mean * sc;
  }
}

// ---------- conv1 apply: block per image, writes NHWC bf16 ----------
__global__ __launch_bounds__(256) void conv1_apply_k(
    const float* __restrict__ x, const float* __restrict__ w1,
    const float* __restrict__ b1, const float* __restrict__ bnp,
    bf16* __restrict__ pooled1)
{
  int img = blockIdx.x, t = threadIdx.x;
  __shared__ __align__(16) float xs[1024];
  __shared__ float wsm[288 + 96];
  ((float4*)xs)[t] = ((const float4*)(x + img * 1024))[t];
  for (int i = t; i < 288; i += 256) wsm[i] = w1[i];
  if (t < 32) { wsm[288 + t] = b1[t]; wsm[320 + t] = bnp[2 * t]; wsm[352 + t] = bnp[2 * t + 1]; }
  __syncthreads();
  bf16* outp = pooled1 + img * 7200;
  for (int idx = t; idx < 7200; idx += 256) {
    int c = idx & 31, pp = idx >> 5;          // NHWC: fast index = channel
    int py = pp / 15, px = pp - py * 15;
    int y0 = 2 * py, x0 = 2 * px;
    const float* wc = wsm + c * 9;
    float bias = wsm[288 + c], sc = wsm[320 + c], sh = wsm[352 + c];
    float r = 0.f;
#pragma unroll
    for (int i = 0; i < 2; ++i)
#pragma unroll
      for (int j = 0; j < 2; ++j) {
        const float* r0 = xs + (y0 + i) * 32 + x0 + j;
        float v = bias;
        v = fmaf(r0[0], wc[0], v);  v = fmaf(r0[1], wc[1], v);  v = fmaf(r0[2], wc[2], v);
        v = fmaf(r0[32], wc[3], v); v = fmaf(r0[33], wc[4], v); v = fmaf(r0[34], wc[5], v);
        v = fmaf(r0[64], wc[6], v); v = fmaf(r0[65], wc[7], v); v = fmaf(r0[66], wc[8], v);
        r += fmaxf(fmaf(v, sc, sh), 0.f);
      }
    outp[idx] = f2b(r * 0.25f);               // idx == pp*32 + c
  }
}

// ---------- implicit-GEMM conv via MFMA: NHWC bf16 in, [img][oc][pix] out ----------
// wave = 16-pixel x 32-oc tile; K = 9 taps x 32 ic; B-frags preloaded, grid-stride M
template <int IN_W, int OUT_W, int OUT_PIX, bool OUT_BF16>
__global__ __launch_bounds__(256) void conv_mfma_k(
    const bf16* __restrict__ in, const bf16* __restrict__ wb,
    void* __restrict__ outv, int ntiles)
{
  constexpr int IN_PIX = IN_W * IN_W;
  int t = threadIdx.x, lane = t & 63;
  int m = lane & 15, kg = lane >> 4;
  const short* wbs = (const short*)wb;
  v8s bfr[9][2];
#pragma unroll
  for (int s = 0; s < 9; ++s)
#pragma unroll
    for (int ob = 0; ob < 2; ++ob)
#pragma unroll
      for (int j = 0; j < 8; ++j)
        bfr[s][ob][j] = wbs[(s * 32 + kg * 8 + j) * 32 + ob * 16 + m];

  int gwave = blockIdx.x * 4 + (t >> 6);
  int nw = gridDim.x * 4;
  for (int tile = gwave; tile < ntiles; tile += nw) {
    unsigned p = tile * 16 + m;
    unsigned img = p / OUT_PIX, pix = p - img * OUT_PIX;
    unsigned y = pix / OUT_W, x = pix - y * OUT_W;
    const bf16* ap = in + img * (IN_PIX * 32) + (y * IN_W + x) * 32 + kg * 8;
    v4f acc0 = {0.f, 0.f, 0.f, 0.f}, acc1 = {0.f, 0.f, 0.f, 0.f};
#pragma unroll
    for (int ky = 0; ky < 3; ++ky)
#pragma unroll
      for (int kx = 0; kx < 3; ++kx) {
        v8s a = *(const v8s*)(ap + (ky * IN_W + kx) * 32);
        acc0 = __builtin_amdgcn_mfma_f32_16x16x32_bf16(a, bfr[ky * 3 + kx][0], acc0, 0, 0, 0);
        acc1 = __builtin_amdgcn_mfma_f32_16x16x32_bf16(a, bfr[ky * 3 + kx][1], acc1, 0, 0, 0);
      }
#pragma unroll
    for (int j = 0; j < 4; ++j) {
      unsigned pr = tile * 16 + kg * 4 + j;          // C row = (lane>>4)*4 + reg
      unsigned img2 = pr / OUT_PIX, pix2 = pr - img2 * OUT_PIX;
      unsigned base = img2 * (32 * OUT_PIX) + pix2;
      if (OUT_BF16) {
        bf16* o = (bf16*)outv;
        o[base + m * OUT_PIX] = f2b(acc0[j]);
        o[base + (16 + m) * OUT_PIX] = f2b(acc1[j]);
      } else {
        float* o = (float*)outv;
        o[base + m * OUT_PIX] = acc0[j];
        o[base + (16 + m) * OUT_PIX] = acc1[j];
      }
    }
  }
}

// ---------- conv2 stats partials ----------
__global__ __launch_bounds__(256) void stats2_p_k(
    const bf16* __restrict__ buf, float* __restrict__ partial)
{
  int c = blockIdx.x & 31, slice = blockIdx.x >> 5;
  int t = threadIdx.x;
  float s = 0.f, ss = 0.f;
  int img0 = slice * 256;
  if (t < 169) {
    for (int im = img0; im < img0 + 256; ++im) {
      float v = b2f(buf[im * 5408 + c * 169 + t]);
      s += v; ss = fmaf(v, v, ss);
    }
  }
#pragma unroll
  for (int off = 32; off; off >>= 1) { s += __shfl_down(s, off, 64); ss += __shfl_down(ss, off, 64); }
  __shared__ float rs[4], rss[4];
  int wv = t >> 6, lane = t & 63;
  if (lane == 0) { rs[wv] = s; rss[wv] = ss; }
  __syncthreads();
  if (t == 0) {
    partial[blockIdx.x * 2] = rs[0] + rs[1] + rs[2] + rs[3];
    partial[blockIdx.x * 2 + 1] = rss[0] + rss[1] + rss[2] + rss[3];
  }
}

// ---------- conv3 stats partials ----------
__global__ __launch_bounds__(256) void stats3_p_k(
    const float* __restrict__ buf, float* __restrict__ partial)
{
  int c = blockIdx.x & 31, slice = blockIdx.x >> 5;
  int t = threadIdx.x;
  float s = 0.f, ss = 0.f;
  int img0 = slice * 256;
  for (int f = t; f < 256 * 16; f += 256) {
    int im = img0 + (f >> 4), p = f & 15;
    float v = buf[im * 512 + c * 16 + p];
    s += v; ss = fmaf(v, v, ss);
  }
#pragma unroll
  for (int off = 32; off; off >>= 1) { s += __shfl_down(s, off, 64); ss += __shfl_down(ss, off, 64); }
  __shared__ float rs[4], rss[4];
  int wv = t >> 6, lane = t & 63;
  if (lane == 0) { rs[wv] = s; rss[wv] = ss; }
  __syncthreads();
  if (t == 0) {
    partial[blockIdx.x * 2] = rs[0] + rs[1] + rs[2] + rs[3];
    partial[blockIdx.x * 2 + 1] = rss[0] + rss[1] + rss[2] + rss[3];
  }
}

// ---------- finalize 8-slice partials ----------
__global__ void bn_finalize_slices_k(
    const float* __restrict__ partial, const float* __restrict__ g,
    const float* __restrict__ bt, float* __restrict__ bnp, float invn)
{
  int c = threadIdx.x;
  if (c < 32) {
    float s = 0.f, ss = 0.f;
#pragma unroll
    for (int sl = 0; sl < 8; ++sl) {
      s += partial[(sl * 32 + c) * 2];
      ss += partial[(sl * 32 + c) * 2 + 1];
    }
    float mean = s * invn;
    float var = ss * invn - mean * mean;
    float sc = g[c] / sqrtf(var + EPSV);
    bnp[2 * c] = sc;
    bnp[2 * c + 1] = bt[c] - mean * sc;
  }
}

// ---------- conv2 apply: BN+ReLU+pool -> NHWC bf16 pooled2 ----------
__global__ __launch_bounds__(256) void conv2_apply_k(
    const bf16* __restrict__ in, const float* __restrict__ bnp,
    bf16* __restrict__ out)
{
  int idx = blockIdx.x * 256 + threadIdx.x;  // exactly 2048*32*36
  int img = idx / 1152, r = idx - img * 1152;
  int c = r / 36, pp = r - c * 36;
  int py = pp / 6, px = pp - py * 6;
  const bf16* bp = in + img * 5408 + c * 169 + py * 26 + px * 2;
  float sc = bnp[2 * c], sh = bnp[2 * c + 1];
  float v = fmaxf(fmaf(b2f(bp[0]), sc, sh), 0.f) + fmaxf(fmaf(b2f(bp[1]), sc, sh), 0.f)
          + fmaxf(fmaf(b2f(bp[13]), sc, sh), 0.f) + fmaxf(fmaf(b2f(bp[14]), sc, sh), 0.f);
  out[img * 1152 + pp * 32 + c] = f2b(v * 0.25f);   // NHWC
}

// ---------- conv3 apply + pool + broadcast to 4 beams ----------
__global__ __launch_bounds__(256) void conv3_apply_k(
    const float* __restrict__ in, const float* __restrict__ bnp,
    float* __restrict__ hs)
{
  int idx = blockIdx.x * 256 + threadIdx.x;  // exactly 2048*128
  int img = idx >> 7, r = idx & 127;
  int c = r >> 2, q = r & 3;
  int py = q >> 1, px = q & 1;
  const float* bp = in + img * 512 + c * 16 + py * 8 + px * 2;
  float sc = bnp[2 * c], sh = bnp[2 * c + 1];
  float v = (fmaxf(fmaf(bp[0], sc, sh), 0.f) + fmaxf(fmaf(bp[1], sc, sh), 0.f)
           + fmaxf(fmaf(bp[4], sc, sh), 0.f) + fmaxf(fmaf(bp[5], sc, sh), 0.f)) * 0.25f;
  float* hb = hs + img * 512 + r;
  hb[0] = v; hb[128] = v; hb[256] = v; hb[384] = v;
}

// ---------- naive MoE step (bf16 weights) ----------
__global__ __launch_bounds__(256) void moe_naive_k(
    const float* __restrict__ hin, float* __restrict__ hout,
    const float* __restrict__ traj, const bf16* __restrict__ Web,
    const float* __restrict__ be, int step)
{
  int gid = blockIdx.x * 256 + threadIdx.x;  // exactly 8192*128
  int row = gid >> 7, h = gid & 127;
  float4 tv = ((const float4*)traj)[step * 8192 + row];
  int e = 0; float bv = tv.x;
  if (tv.y > bv) { bv = tv.y; e = 1; }
  if (tv.z > bv) { bv = tv.z; e = 2; }
  if (tv.w > bv) { bv = tv.w; e = 3; }
  float v;
  if (e == 3) {
    v = hin[row * 128 + h];
  } else {
    const float* hr = hin + row * 128;       // wave-uniform row
    const bf16* wp = Web + e * 16384 + h;
    float a0 = be[e * 128 + h], a1 = 0.f, a2 = 0.f, a3 = 0.f;
#pragma unroll 8
    for (int d = 0; d < 128; d += 4) {
      a0 = fmaf(hr[d],     b2f(wp[d * 128]),       a0);
      a1 = fmaf(hr[d + 1], b2f(wp[(d + 1) * 128]), a1);
      a2 = fmaf(hr[d + 2], b2f(wp[(d + 2) * 128]), a2);
      a3 = fmaf(hr[d + 3], b2f(wp[(d + 3) * 128]), a3);
    }
    v = (a0 + a1) + (a2 + a3);
  }
  hout[gid] = fmaxf(v, 0.f);
}

// ---------- naive head ----------
__global__ __launch_bounds__(256) void final_naive_k(
    const float* __restrict__ hs, const float* __restrict__ Wo,
    const float* __restrict__ bo, const float* __restrict__ sv,
    float* __restrict__ out)
{
  int gid = blockIdx.x * 256 + threadIdx.x;  // exactly 8192*10
  int row = gid / 10, o = gid - row * 10;
  float ps = 1.f;
#pragma unroll
  for (int i = 0; i < 12; ++i) ps *= sv[i];
  const float* hr = hs + row * 128;
  const float* wr = Wo + o * 128;
  float a = bo[o];
#pragma unroll 8
  for (int d = 0; d < 128; ++d) a = fmaf(hr[d], wr[d], a);
  out[gid] = a * ps;
}

extern "C" void kernel_launch(void* const* d_in, const int* in_sizes, int n_in,
                              void* d_out, int out_size, void* d_ws, size_t ws_size,
                              hipStream_t stream)
{
  float* out = (float*)d_out;

  static const int EXP[19] = {2097152, 98304, 12, 288, 32, 9216, 32, 9216, 32,
                              32, 32, 32, 32, 32, 32, 49152, 384, 1280, 10};
  int bad = -1;
  if (n_in != 19) bad = 100;
  else
    for (int i = 0; i < 19; ++i)
      if (in_sizes[i] != EXP[i]) { bad = i; break; }
  if (bad >= 0) {
    fill_k<<<(out_size + 255) / 256, 256, 0, stream>>>(out, 1000.f + 10.f * bad, out_size);
    return;
  }
  const size_t NEED = 73663232;
  if (ws_size < NEED) {
    fill_k<<<(out_size + 255) / 256, 256, 0, stream>>>(
        out, 3000.f + (float)(ws_size >> 20), out_size);
    return;
  }

  const float* x    = (const float*)d_in[0];
  const float* traj = (const float*)d_in[1];
  const float* sv   = (const float*)d_in[2];
  const float* c1w  = (const float*)d_in[3];
  const float* c1b  = (const float*)d_in[4];
  const float* c2w  = (const float*)d_in[5];
  const float* c3w  = (const float*)d_in[7];
  const float* g1   = (const float*)d_in[9];
  const float* bt1  = (const float*)d_in[10];
  const float* g2   = (const float*)d_in[11];
  const float* bt2  = (const float*)d_in[12];
  const float* g3   = (const float*)d_in[13];
  const float* bt3  = (const float*)d_in[14];
  const float* We   = (const float*)d_in[15];
  const float* be   = (const float*)d_in[16];
  const float* Wo   = (const float*)d_in[17];
  const float* bo   = (const float*)d_in[18];

  char* w = (char*)d_ws;
  bf16*  pooled1  = (bf16*)(w + 0);          // NHWC bf16, 29,491,200 B
  bf16*  conv2out = (bf16*)(w + 29491200);   // [img][oc][169] bf16, 22,151,168 B
  bf16*  pooled2  = (bf16*)(w + 51642368);   // NHWC bf16, 4,718,592 B
  bf16*  Web      = (bf16*)(w + 56360960);   // 98,304 B
  float* conv3out = (float*)(w + 61079552);  // [img][oc][16] f32, 4,194,304 B
  float* hsA      = (float*)(w + 65273856);  // 4,194,304 B
  float* hsB      = (float*)(w + 69468160);  // 4,194,304 B
  float* bnp1     = (float*)(w + 73662464);
  float* bnp2     = (float*)(w + 73662720);
  float* bnp3     = (float*)(w + 73662976);  // end 73,663,232 B
  // short-lived aliases (lifetimes verified disjoint):
  float* partial1 = (float*)conv2out;        // dead before conv2 mfma writes
  float* partial2 = (float*)pooled2;         // dead before conv2_apply writes
  float* partial3 = (float*)hsA;             // dead before conv3_apply writes
  bf16*  w2b      = (bf16*)hsB;              // read until conv2 mfma; hsB written at moe step 0
  bf16*  w3b      = w2b + 9216;              // read until conv3 mfma

  prep_w_k<<<264, 256, 0, stream>>>(c2w, c3w, We, w2b, w3b, Web);
  conv1_stats_p1_k<<<2048, 256, 0, stream>>>(x, c1w, c1b, partial1);
  bn_reduce_partial_k<<<32, 256, 0, stream>>>(partial1, g1, bt1, bnp1, 2048,
                                              1.f / (2048.f * 900.f));
  conv1_apply_k<<<2048, 256, 0, stream>>>(x, c1w, c1b, bnp1, pooled1);
  conv_mfma_k<15, 13, 169, true><<<1024, 256, 0, stream>>>(pooled1, w2b, conv2out, 21632);
  stats2_p_k<<<256, 256, 0, stream>>>(conv2out, partial2);
  bn_finalize_slices_k<<<1, 64, 0, stream>>>(partial2, g2, bt2, bnp2,
                                             1.f / (2048.f * 169.f));
  conv2_apply_k<<<9216, 256, 0, stream>>>(conv2out, bnp2, pooled2);
  conv_mfma_k<6, 4, 16, false><<<256, 256, 0, stream>>>(pooled2, w3b, conv3out, 2048);
  stats3_p_k<<<256, 256, 0, stream>>>(conv3out, partial3);
  bn_finalize_slices_k<<<1, 64, 0, stream>>>(partial3, g3, bt3, bnp3,
                                             1.f / (2048.f * 16.f));
  conv3_apply_k<<<1024, 256, 0, stream>>>(conv3out, bnp3, hsA);
  moe_naive_k<<<4096, 256, 0, stream>>>(hsA, hsB, traj, Web, be, 0);
  moe_naive_k<<<4096, 256, 0, stream>>>(hsB, hsA, traj, Web, be, 1);
  moe_naive_k<<<4096, 256, 0, stream>>>(hsA, hsB, traj, Web, be, 2);
  final_naive_k<<<320, 256, 0, stream>>>(hsB, Wo, bo, sv, out);
}

// Round 7
// 216.138 us; speedup vs baseline: 8.5220x; 1.4161x over previous
//
#include <hip/hip_runtime.h>
#include <hip/hip_bf16.h>

#define EPSV 1e-5f
typedef __hip_bfloat16 bf16;
typedef __attribute__((ext_vector_type(8))) short v8s;
typedef __attribute__((ext_vector_type(4))) float v4f;
__device__ __forceinline__ float b2f(bf16 v) { return __bfloat162float(v); }
__device__ __forceinline__ bf16 f2b(float v) { return __float2bfloat16(v); }

__global__ __launch_bounds__(256) void fill_k(float* __restrict__ out, float val, int n)
{
  int i = blockIdx.x * 256 + threadIdx.x;
  if (i < n) out[i] = val;
}

// ---------- prep: pack conv2/conv3 weights to [(s)*32+ic][oc] bf16; We -> bf16 ----------
__global__ __launch_bounds__(256) void prep_w_k(
    const float* __restrict__ w2, const float* __restrict__ w3,
    const float* __restrict__ We,
    bf16* __restrict__ w2b, bf16* __restrict__ w3b, bf16* __restrict__ Web)
{
  int i = blockIdx.x * 256 + threadIdx.x;
  if (i < 9216) {
    int oc = i & 31, k = i >> 5, s = k >> 5, ic = k & 31;
    w2b[i] = f2b(w2[oc * 288 + ic * 9 + s]);
  } else if (i < 18432) {
    int j = i - 9216;
    int oc = j & 31, k = j >> 5, s = k >> 5, ic = k & 31;
    w3b[j] = f2b(w3[oc * 288 + ic * 9 + s]);
  } else if (i < 18432 + 49152) {
    int j = i - 18432;
    Web[j] = f2b(We[j]);
  }
}

// ---------- conv1 stats pass 1 ----------
__global__ __launch_bounds__(256) void conv1_stats_p1_k(
    const float* __restrict__ x, const float* __restrict__ w1,
    const float* __restrict__ b1, float* __restrict__ partial1)
{
  int img = blockIdx.x, t = threadIdx.x;
  __shared__ __align__(16) float xs[1024];
  ((float4*)xs)[t] = ((const float4*)(x + img * 1024))[t];
  __syncthreads();
  int c = t & 31;
  float w[9];
#pragma unroll
  for (int j = 0; j < 9; ++j) w[j] = w1[c * 9 + j];
  float bias = b1[c];
  float s = 0.f, ss = 0.f;
  for (int p = (t >> 5); p < 900; p += 8) {
    int y = p / 30, xx = p - y * 30;
    const float* r0 = xs + y * 32 + xx;
    float v = bias;
    v = fmaf(r0[0], w[0], v);  v = fmaf(r0[1], w[1], v);  v = fmaf(r0[2], w[2], v);
    v = fmaf(r0[32], w[3], v); v = fmaf(r0[33], w[4], v); v = fmaf(r0[34], w[5], v);
    v = fmaf(r0[64], w[6], v); v = fmaf(r0[65], w[7], v); v = fmaf(r0[66], w[8], v);
    s += v; ss = fmaf(v, v, ss);
  }
  s += __shfl_xor(s, 32, 64);
  ss += __shfl_xor(ss, 32, 64);
  __shared__ float red[4][32][2];
  int wv = t >> 6, lane = t & 63;
  if (lane < 32) { red[wv][lane][0] = s; red[wv][lane][1] = ss; }
  __syncthreads();
  if (t < 64) {
    int cc = t >> 1, j = t & 1;
    partial1[img * 64 + t] = red[0][cc][j] + red[1][cc][j] + red[2][cc][j] + red[3][cc][j];
  }
}

// ---------- generic partial reduce -> scale/shift ----------
__global__ __launch_bounds__(256) void bn_reduce_partial_k(
    const float* __restrict__ partial, const float* __restrict__ g,
    const float* __restrict__ bt, float* __restrict__ bnp,
    int nimg, float invn)
{
  int c = blockIdx.x, t = threadIdx.x;
  float s = 0.f, ss = 0.f;
  for (int i = t; i < nimg; i += 256) {
    s += partial[i * 64 + c * 2];
    ss += partial[i * 64 + c * 2 + 1];
  }
#pragma unroll
  for (int off = 32; off; off >>= 1) { s += __shfl_down(s, off, 64); ss += __shfl_down(ss, off, 64); }
  __shared__ float rs[4], rss[4];
  int wv = t >> 6, lane = t & 63;
  if (lane == 0) { rs[wv] = s; rss[wv] = ss; }
  __syncthreads();
  if (t == 0) {
    s = rs[0] + rs[1] + rs[2] + rs[3];
    ss = rss[0] + rss[1] + rss[2] + rss[3];
    float mean = s * invn;
    float var = ss * invn - mean * mean;
    float sc = g[c] / sqrtf(var + EPSV);
    bnp[2 * c] = sc;
    bnp[2 * c + 1] = bt[c] - mean * sc;
  }
}

// ---------- conv1 apply: block per image, writes NHWC bf16 ----------
__global__ __launch_bounds__(256) void conv1_apply_k(
    const float* __restrict__ x, const float* __restrict__ w1,
    const float* __restrict__ b1, const float* __restrict__ bnp,
    bf16* __restrict__ pooled1)
{
  int img = blockIdx.x, t = threadIdx.x;
  __shared__ __align__(16) float xs[1024];
  __shared__ float wsm[288 + 96];
  ((float4*)xs)[t] = ((const float4*)(x + img * 1024))[t];
  for (int i = t; i < 288; i += 256) wsm[i] = w1[i];
  if (t < 32) { wsm[288 + t] = b1[t]; wsm[320 + t] = bnp[2 * t]; wsm[352 + t] = bnp[2 * t + 1]; }
  __syncthreads();
  bf16* outp = pooled1 + img * 7200;
  for (int idx = t; idx < 7200; idx += 256) {
    int c = idx & 31, pp = idx >> 5;          // NHWC: fast index = channel
    int py = pp / 15, px = pp - py * 15;
    int y0 = 2 * py, x0 = 2 * px;
    const float* wc = wsm + c * 9;
    float bias = wsm[288 + c], sc = wsm[320 + c], sh = wsm[352 + c];
    float r = 0.f;
#pragma unroll
    for (int i = 0; i < 2; ++i)
#pragma unroll
      for (int j = 0; j < 2; ++j) {
        const float* r0 = xs + (y0 + i) * 32 + x0 + j;
        float v = bias;
        v = fmaf(r0[0], wc[0], v);  v = fmaf(r0[1], wc[1], v);  v = fmaf(r0[2], wc[2], v);
        v = fmaf(r0[32], wc[3], v); v = fmaf(r0[33], wc[4], v); v = fmaf(r0[34], wc[5], v);
        v = fmaf(r0[64], wc[6], v); v = fmaf(r0[65], wc[7], v); v = fmaf(r0[66], wc[8], v);
        r += fmaxf(fmaf(v, sc, sh), 0.f);
      }
    outp[idx] = f2b(r * 0.25f);
  }
}

// ---------- implicit-GEMM conv via MFMA, NHWC in/out, fused BN-stats partials ----------
template <int IN_W, int OUT_W, int OUT_PIX, bool OUT_BF16>
__global__ __launch_bounds__(256) void conv_mfma_k(
    const bf16* __restrict__ in, const bf16* __restrict__ wb,
    void* __restrict__ outv, float* __restrict__ partial, int ntiles)
{
  constexpr int IN_PIX = IN_W * IN_W;
  int t = threadIdx.x, lane = t & 63;
  int m = lane & 15, kg = lane >> 4;
  const short* wbs = (const short*)wb;
  v8s bfr[9][2];
#pragma unroll
  for (int s = 0; s < 9; ++s)
#pragma unroll
    for (int ob = 0; ob < 2; ++ob)
#pragma unroll
      for (int j = 0; j < 8; ++j)
        bfr[s][ob][j] = wbs[(s * 32 + kg * 8 + j) * 32 + ob * 16 + m];

  float rs0 = 0.f, rss0 = 0.f, rs1 = 0.f, rss1 = 0.f;
  int gwave = blockIdx.x * 4 + (t >> 6);
  int nw = gridDim.x * 4;
  for (int tile = gwave; tile < ntiles; tile += nw) {
    unsigned p = tile * 16 + m;
    unsigned img = p / OUT_PIX, pix = p - img * OUT_PIX;
    unsigned y = pix / OUT_W, x = pix - y * OUT_W;
    const bf16* ap = in + img * (IN_PIX * 32) + (y * IN_W + x) * 32 + kg * 8;
    v4f acc0 = {0.f, 0.f, 0.f, 0.f}, acc1 = {0.f, 0.f, 0.f, 0.f};
#pragma unroll
    for (int ky = 0; ky < 3; ++ky)
#pragma unroll
      for (int kx = 0; kx < 3; ++kx) {
        v8s a = *(const v8s*)(ap + (ky * IN_W + kx) * 32);
        acc0 = __builtin_amdgcn_mfma_f32_16x16x32_bf16(a, bfr[ky * 3 + kx][0], acc0, 0, 0, 0);
        acc1 = __builtin_amdgcn_mfma_f32_16x16x32_bf16(a, bfr[ky * 3 + kx][1], acc1, 0, 0, 0);
      }
#pragma unroll
    for (int j = 0; j < 4; ++j) {
      rs0 += acc0[j]; rss0 = fmaf(acc0[j], acc0[j], rss0);
      rs1 += acc1[j]; rss1 = fmaf(acc1[j], acc1[j], rss1);
      unsigned pr = tile * 16 + kg * 4 + j;          // C row = (lane>>4)*4 + reg
      unsigned img2 = pr / OUT_PIX, pix2 = pr - img2 * OUT_PIX;
      unsigned base = (img2 * OUT_PIX + pix2) * 32;  // NHWC
      if (OUT_BF16) {
        bf16* o = (bf16*)outv;
        o[base + m] = f2b(acc0[j]);
        o[base + 16 + m] = f2b(acc1[j]);
      } else {
        float* o = (float*)outv;
        o[base + m] = acc0[j];
        o[base + 16 + m] = acc1[j];
      }
    }
  }
  // stats: sum across kg groups (lanes m, m+16, m+32, m+48)
  rs0 += __shfl_xor(rs0, 16, 64);  rs0 += __shfl_xor(rs0, 32, 64);
  rss0 += __shfl_xor(rss0, 16, 64); rss0 += __shfl_xor(rss0, 32, 64);
  rs1 += __shfl_xor(rs1, 16, 64);  rs1 += __shfl_xor(rs1, 32, 64);
  rss1 += __shfl_xor(rss1, 16, 64); rss1 += __shfl_xor(rss1, 32, 64);
  __shared__ float red[4][32][2];
  int wv = t >> 6;
  if (lane < 16) {
    red[wv][lane][0] = rs0;      red[wv][lane][1] = rss0;
    red[wv][16 + lane][0] = rs1; red[wv][16 + lane][1] = rss1;
  }
  __syncthreads();
  if (t < 64) {
    int cc = t >> 1, j = t & 1;
    partial[blockIdx.x * 64 + t] = red[0][cc][j] + red[1][cc][j] + red[2][cc][j] + red[3][cc][j];
  }
}

// ---------- conv2 apply: NHWC vectorized BN+ReLU+pool 13->6 -> NHWC bf16 ----------
__global__ __launch_bounds__(256) void conv2_apply_k(
    const bf16* __restrict__ in, const float* __restrict__ bnp,
    bf16* __restrict__ out)
{
  int idx = blockIdx.x * 256 + threadIdx.x;  // exactly 2048*36*4
  int img = idx / 144, r = idx - img * 144;
  int pp = r >> 2, c8 = r & 3;
  int py = pp / 6, px = pp - py * 6;
  int ip0 = (2 * py) * 13 + 2 * px;
  const bf16* bp = in + (img * 169 + ip0) * 32 + c8 * 8;
  v8s a = *(const v8s*)bp;
  v8s b = *(const v8s*)(bp + 32);
  v8s cc = *(const v8s*)(bp + 13 * 32);
  v8s d = *(const v8s*)(bp + 14 * 32);
  const float* bn = bnp + c8 * 16;
  union { v8s v; short s[8]; bf16 h[8]; } res;
#pragma unroll
  for (int k = 0; k < 8; ++k) {
    float sc = bn[2 * k], sh = bn[2 * k + 1];
    bf16 av, bv, cv, dv;
    *(short*)&av = a[k]; *(short*)&bv = b[k]; *(short*)&cv = cc[k]; *(short*)&dv = d[k];
    float v = fmaxf(fmaf(b2f(av), sc, sh), 0.f) + fmaxf(fmaf(b2f(bv), sc, sh), 0.f)
            + fmaxf(fmaf(b2f(cv), sc, sh), 0.f) + fmaxf(fmaf(b2f(dv), sc, sh), 0.f);
    res.h[k] = f2b(v * 0.25f);
  }
  *(v8s*)(out + (img * 36 + pp) * 32 + c8 * 8) = res.v;
}

// ---------- conv3 apply + pool + broadcast to 4 beams (NHWC fp32 in) ----------
__global__ __launch_bounds__(256) void conv3_apply_k(
    const float* __restrict__ in, const float* __restrict__ bnp,
    float* __restrict__ hs)
{
  int idx = blockIdx.x * 256 + threadIdx.x;  // exactly 2048*128
  int img = idx >> 7, r = idx & 127;
  int c = r >> 2, q = r & 3;
  int py = q >> 1, px = q & 1;
  int p0 = py * 8 + px * 2;
  const float* bp = in + img * 512 + c;
  float sc = bnp[2 * c], sh = bnp[2 * c + 1];
  float v = (fmaxf(fmaf(bp[p0 * 32], sc, sh), 0.f)
           + fmaxf(fmaf(bp[(p0 + 1) * 32], sc, sh), 0.f)
           + fmaxf(fmaf(bp[(p0 + 4) * 32], sc, sh), 0.f)
           + fmaxf(fmaf(bp[(p0 + 5) * 32], sc, sh), 0.f)) * 0.25f;
  float* hb = hs + img * 512 + r;
  hb[0] = v; hb[128] = v; hb[256] = v; hb[384] = v;
}

// ---------- naive MoE step (bf16 weights) ----------
__global__ __launch_bounds__(256) void moe_naive_k(
    const float* __restrict__ hin, float* __restrict__ hout,
    const float* __restrict__ traj, const bf16* __restrict__ Web,
    const float* __restrict__ be, int step)
{
  int gid = blockIdx.x * 256 + threadIdx.x;  // exactly 8192*128
  int row = gid >> 7, h = gid & 127;
  float4 tv = ((const float4*)traj)[step * 8192 + row];
  int e = 0; float bv = tv.x;
  if (tv.y > bv) { bv = tv.y; e = 1; }
  if (tv.z > bv) { bv = tv.z; e = 2; }
  if (tv.w > bv) { bv = tv.w; e = 3; }
  float v;
  if (e == 3) {
    v = hin[row * 128 + h];
  } else {
    const float* hr = hin + row * 128;       // wave-uniform row
    const bf16* wp = Web + e * 16384 + h;
    float a0 = be[e * 128 + h], a1 = 0.f, a2 = 0.f, a3 = 0.f;
#pragma unroll 8
    for (int d = 0; d < 128; d += 4) {
      a0 = fmaf(hr[d],     b2f(wp[d * 128]),       a0);
      a1 = fmaf(hr[d + 1], b2f(wp[(d + 1) * 128]), a1);
      a2 = fmaf(hr[d + 2], b2f(wp[(d + 2) * 128]), a2);
      a3 = fmaf(hr[d + 3], b2f(wp[(d + 3) * 128]), a3);
    }
    v = (a0 + a1) + (a2 + a3);
  }
  hout[gid] = fmaxf(v, 0.f);
}

// ---------- naive head ----------
__global__ __launch_bounds__(256) void final_naive_k(
    const float* __restrict__ hs, const float* __restrict__ Wo,
    const float* __restrict__ bo, const float* __restrict__ sv,
    float* __restrict__ out)
{
  int gid = blockIdx.x * 256 + threadIdx.x;  // exactly 8192*10
  int row = gid / 10, o = gid - row * 10;
  float ps = 1.f;
#pragma unroll
  for (int i = 0; i < 12; ++i) ps *= sv[i];
  const float* hr = hs + row * 128;
  const float* wr = Wo + o * 128;
  float a = bo[o];
#pragma unroll 8
  for (int d = 0; d < 128; ++d) a = fmaf(hr[d], wr[d], a);
  out[gid] = a * ps;
}

extern "C" void kernel_launch(void* const* d_in, const int* in_sizes, int n_in,
                              void* d_out, int out_size, void* d_ws, size_t ws_size,
                              hipStream_t stream)
{
  float* out = (float*)d_out;

  static const int EXP[19] = {2097152, 98304, 12, 288, 32, 9216, 32, 9216, 32,
                              32, 32, 32, 32, 32, 32, 49152, 384, 1280, 10};
  int bad = -1;
  if (n_in != 19) bad = 100;
  else
    for (int i = 0; i < 19; ++i)
      if (in_sizes[i] != EXP[i]) { bad = i; break; }
  if (bad >= 0) {
    fill_k<<<(out_size + 255) / 256, 256, 0, stream>>>(out, 1000.f + 10.f * bad, out_size);
    return;
  }
  const size_t NEED = 73663232;
  if (ws_size < NEED) {
    fill_k<<<(out_size + 255) / 256, 256, 0, stream>>>(
        out, 3000.f + (float)(ws_size >> 20), out_size);
    return;
  }

  const float* x    = (const float*)d_in[0];
  const float* traj = (const float*)d_in[1];
  const float* sv   = (const float*)d_in[2];
  const float* c1w  = (const float*)d_in[3];
  const float* c1b  = (const float*)d_in[4];
  const float* c2w  = (const float*)d_in[5];
  const float* c3w  = (const float*)d_in[7];
  const float* g1   = (const float*)d_in[9];
  const float* bt1  = (const float*)d_in[10];
  const float* g2   = (const float*)d_in[11];
  const float* bt2  = (const float*)d_in[12];
  const float* g3   = (const float*)d_in[13];
  const float* bt3  = (const float*)d_in[14];
  const float* We   = (const float*)d_in[15];
  const float* be   = (const float*)d_in[16];
  const float* Wo   = (const float*)d_in[17];
  const float* bo   = (const float*)d_in[18];

  char* w = (char*)d_ws;
  bf16*  pooled1  = (bf16*)(w + 0);          // NHWC bf16, 29,491,200 B
  bf16*  conv2out = (bf16*)(w + 29491200);   // NHWC bf16, 22,151,168 B
  bf16*  pooled2  = (bf16*)(w + 51642368);   // NHWC bf16, 4,718,592 B
  bf16*  Web      = (bf16*)(w + 56360960);   // 98,304 B
  float* conv3out = (float*)(w + 61079552);  // NHWC f32, 4,194,304 B
  float* hsA      = (float*)(w + 65273856);  // 4,194,304 B
  float* hsB      = (float*)(w + 69468160);  // 4,194,304 B
  float* bnp1     = (float*)(w + 73662464);
  float* bnp2     = (float*)(w + 73662720);
  float* bnp3     = (float*)(w + 73662976);  // end 73,663,232 B
  // short-lived aliases (lifetimes verified disjoint):
  float* partial1 = (float*)conv2out;        // dead before conv2 mfma writes conv2out
  float* partial2 = (float*)pooled2;         // 1024*64 f32 = 256KB; dead before conv2_apply writes
  float* partial3 = (float*)hsA;             // 256*64 f32 = 64KB; dead before conv3_apply writes
  bf16*  w2b      = (bf16*)hsB;              // read until conv2 mfma; hsB written at moe step 0
  bf16*  w3b      = w2b + 9216;              // read until conv3 mfma

  prep_w_k<<<264, 256, 0, stream>>>(c2w, c3w, We, w2b, w3b, Web);
  conv1_stats_p1_k<<<2048, 256, 0, stream>>>(x, c1w, c1b, partial1);
  bn_reduce_partial_k<<<32, 256, 0, stream>>>(partial1, g1, bt1, bnp1, 2048,
                                              1.f / (2048.f * 900.f));
  conv1_apply_k<<<2048, 256, 0, stream>>>(x, c1w, c1b, bnp1, pooled1);
  conv_mfma_k<15, 13, 169, true><<<1024, 256, 0, stream>>>(pooled1, w2b, conv2out,
                                                           partial2, 21632);
  bn_reduce_partial_k<<<32, 256, 0, stream>>>(partial2, g2, bt2, bnp2, 1024,
                                              1.f / (2048.f * 169.f));
  conv2_apply_k<<<1152, 256, 0, stream>>>(conv2out, bnp2, pooled2);
  conv_mfma_k<6, 4, 16, false><<<256, 256, 0, stream>>>(pooled2, w3b, conv3out,
                                                        partial3, 2048);
  bn_reduce_partial_k<<<32, 256, 0, stream>>>(partial3, g3, bt3, bnp3, 256,
                                              1.f / (2048.f * 16.f));
  conv3_apply_k<<<1024, 256, 0, stream>>>(conv3out, bnp3, hsA);
  moe_naive_k<<<4096, 256, 0, stream>>>(hsA, hsB, traj, Web, be, 0);
  moe_naive_k<<<4096, 256, 0, stream>>>(hsB, hsA, traj, Web, be, 1);
  moe_naive_k<<<4096, 256, 0, stream>>>(hsA, hsB, traj, Web, be, 2);
  final_naive_k<<<320, 256, 0, stream>>>(hsB, Wo, bo, sv, out);
}